// Round 5
// baseline (1143.165 us; speedup 1.0000x reference)
//
#include <hip/hip_runtime.h>

// B=4, T=8, H=W=16, C=F=256, gates 4F=1024. K = 9*256 = 2304.
// Round 5: rec conv rewritten barrier-free — A/B fragments read directly
// from L2-resident global buffers into VGPRs with distance-2 register
// prefetch (no LDS, no barriers, no gl16). Big conv: + s_setprio around
// MFMA cluster (T5). Everything else unchanged from round 4.
#define HW      256
#define COUT    1024
#define TSTEPS  8
#define BN_EPS  1e-3f
#define KTOT    2304
#define KQN     72          // KTOT/32

typedef unsigned short u16;
typedef unsigned int   u32;
typedef __attribute__((ext_vector_type(8))) _Float16 v8h;  // 8 x fp16
typedef __attribute__((ext_vector_type(4))) float v4f;

__device__ __forceinline__ u16 f2h(float x) {
    _Float16 h = (_Float16)x;          // v_cvt_f16_f32, RTNE
    return *(u16*)&h;
}
__device__ __forceinline__ float hsig(float x) {
    return fminf(fmaxf(0.2f * x + 0.5f, 0.f), 1.f);
}

typedef __attribute__((address_space(1))) const unsigned int gas_u32;
typedef __attribute__((address_space(3))) unsigned int las_u32;
__device__ __forceinline__ void gl16(const void* g, void* l) {
    __builtin_amdgcn_global_load_lds((gas_u32*)g, (las_u32*)l, 16, 0, 0);
}

// ---------------------------------------------------------------------------
// Big input conv: M=8192, N'=1024 gate-interleaved, K=2304. BM=BN=128,
// 4 waves (2x2), depth-4 LDS pipeline, setprio around MFMA (T5).
// ---------------------------------------------------------------------------
__global__ __launch_bounds__(256) void conv_big_k(
    const u16* __restrict__ apad,     // (32,18,18,256) fp16 zero-padded
    const u16* __restrict__ wT,       // (1024 n', 2304) fp16
    const float* __restrict__ bias,   // (1024) original n order
    float* __restrict__ out)          // (8192, 1024) n' order
{
    constexpr int BM = 128, BN = 128, AR = 32, BR = 32, ANI = 2, BNI = 2;
    constexpr int MI = 4, NI = 4;
    constexpr int BUF = (BM + BN) * 32;          // u16 per buffer
    __shared__ u16 lds[4 * BUF];                 // 64 KiB

    const int bid = blockIdx.x;
    const int by = bid & 7, bx = bid >> 3;
    const int m0 = bx * BM, n0 = by * BN;
    const int tid = threadIdx.x, lane = tid & 63, w = tid >> 6;
    const int wr = w >> 1, wc = w & 1;
    const int swz = (lane & 3) ^ ((lane >> 2) & 3) ^ ((lane >> 4) & 3);

    const char* a_src[ANI];
    #pragma unroll
    for (int i = 0; i < ANI; ++i) {
        int m = m0 + w * AR + i * 16 + (lane >> 2);
        int img = m >> 8, pix = m & 255, yy = pix >> 4, xx = pix & 15;
        a_src[i] = (const char*)apad +
                   ((((long)img * 18 + yy) * 18 + xx) * 256) * 2 + swz * 16;
    }
    const char* b_src[BNI];
    #pragma unroll
    for (int i = 0; i < BNI; ++i) {
        int n = n0 + w * BR + i * 16 + (lane >> 2);
        b_src[i] = (const char*)wT + ((long)n * KTOT) * 2 + swz * 16;
    }

    v4f acc[MI][NI];
    #pragma unroll
    for (int mi = 0; mi < MI; ++mi)
        #pragma unroll
        for (int ni = 0; ni < NI; ++ni) acc[mi][ni] = (v4f)0.f;

#define STAGE_B(J) { int j_ = (J); int dxy = j_ >> 3, c32 = j_ & 7;          \
    int dy = (dxy * 11) >> 5; int dx = dxy - dy * 3;                         \
    int aoff = ((dy * 18 + dx) * 256 + c32 * 32) * 2; int boff = j_ * 64;    \
    u16* Ab_ = lds + (j_ & 3) * BUF; u16* Bb_ = Ab_ + BM * 32;               \
    _Pragma("unroll") for (int i = 0; i < ANI; ++i)                          \
        gl16(a_src[i] + aoff, (char*)Ab_ + (w * AR + i * 16) * 64);          \
    _Pragma("unroll") for (int i = 0; i < BNI; ++i)                          \
        gl16(b_src[i] + boff, (char*)Bb_ + (w * BR + i * 16) * 64); }

#define COMPUTE_B(KQ) { u16* Ab_ = lds + ((KQ) & 3) * BUF;                   \
    u16* Bb_ = Ab_ + BM * 32; v8h af[MI], bf[NI];                            \
    _Pragma("unroll") for (int mi = 0; mi < MI; ++mi)                        \
        af[mi] = *(const v8h*)&Ab_[(wr * 64 + mi * 16 + (lane & 15)) * 32 + swz * 8]; \
    _Pragma("unroll") for (int ni = 0; ni < NI; ++ni)                        \
        bf[ni] = *(const v8h*)&Bb_[(wc * 64 + ni * 16 + (lane & 15)) * 32 + swz * 8]; \
    __builtin_amdgcn_s_setprio(1);                                           \
    _Pragma("unroll") for (int mi = 0; mi < MI; ++mi)                        \
        _Pragma("unroll") for (int ni = 0; ni < NI; ++ni)                    \
            acc[mi][ni] = __builtin_amdgcn_mfma_f32_16x16x32_f16(af[mi], bf[ni], acc[mi][ni], 0, 0, 0); \
    __builtin_amdgcn_s_setprio(0); }

    STAGE_B(0); STAGE_B(1); STAGE_B(2);
    for (int kq = 0; kq < KQN - 3; ++kq) {
        asm volatile("s_waitcnt vmcnt(8)" ::: "memory");
        __builtin_amdgcn_s_barrier();
        __builtin_amdgcn_sched_barrier(0);
        STAGE_B(kq + 3);
        COMPUTE_B(kq);
    }
    asm volatile("s_waitcnt vmcnt(8)" ::: "memory");
    __builtin_amdgcn_s_barrier();
    __builtin_amdgcn_sched_barrier(0);
    COMPUTE_B(KQN - 3);
    asm volatile("s_waitcnt vmcnt(4)" ::: "memory");
    __builtin_amdgcn_s_barrier();
    __builtin_amdgcn_sched_barrier(0);
    COMPUTE_B(KQN - 2);
    asm volatile("s_waitcnt vmcnt(0)" ::: "memory");
    __builtin_amdgcn_s_barrier();
    __builtin_amdgcn_sched_barrier(0);
    COMPUTE_B(KQN - 1);
#undef STAGE_B
#undef COMPUTE_B

    // epilogue: + bias (remapped from n' to original n), store fp32 n'-order
    #pragma unroll
    for (int mi = 0; mi < MI; ++mi) {
        #pragma unroll
        for (int ni = 0; ni < NI; ++ni) {
            int mrow = m0 + wr * 64 + mi * 16 + ((lane >> 4) << 2);
            int ncol = n0 + wc * 64 + ni * 16 + (lane & 15);
            float b0 = bias[(ncol & 3) * 256 + (ncol >> 2)];
            #pragma unroll
            for (int r = 0; r < 4; ++r)
                out[(long)(mrow + r) * COUT + ncol] = acc[mi][ni][r] + b0;
        }
    }
}

// ---------------------------------------------------------------------------
// Recurrent conv + fused LSTM cell — barrier-free, LDS-free.
// M=1024, N'=1024, 64x64 tiles, 256 blocks (1/CU). A/B fragments read
// directly from L2-resident global; distance-2 register prefetch.
// ---------------------------------------------------------------------------
__global__ __launch_bounds__(256) void rec_fused_k(
    const u16* __restrict__ ph_in,    // (4,18,18,256) fp16  h_{t-1}
    const u16* __restrict__ wT,       // (1024 n', 2304) fp16
    const float* __restrict__ xg,     // (8192, 1024) n' order (incl. bias)
    float* __restrict__ cbuf,         // (4,256,256)
    float* __restrict__ hs,           // (4,8,256,256)
    u16* __restrict__ ph_out,         // (4,18,18,256) fp16  h_t
    int t)
{
    const int bid = blockIdx.x;                  // XCD swizzle: n-slices per XCD
    const int k8 = bid & 7, q = bid >> 3;
    const int by = 2 * k8 + (q >> 4), bx = q & 15;
    const int m0 = bx * 64, n0 = by * 64;
    const int tid = threadIdx.x, lane = tid & 63, w = tid >> 6;
    const int wr = w >> 1, wc = w & 1;
    const int fr = lane & 15, kc = lane >> 4;    // frag row, k-chunk

    // per-lane fragment base pointers (A: pixel rows; B: wT rows)
    const char* abase[2];
    #pragma unroll
    for (int mi = 0; mi < 2; ++mi) {
        int m = m0 + wr * 32 + mi * 16 + fr;
        int img = m >> 8, pix = m & 255, yy = pix >> 4, xx = pix & 15;
        abase[mi] = (const char*)ph_in +
                    (((((long)img * 18 + yy) * 18 + xx) * 256) + kc * 8) * 2;
    }
    const char* bbase[2];
    #pragma unroll
    for (int ni = 0; ni < 2; ++ni) {
        int n = n0 + wc * 32 + ni * 16 + fr;
        bbase[ni] = (const char*)wT + ((long)n * KTOT + kc * 8) * 2;
    }

    v4f acc00 = (v4f)0.f, acc01 = (v4f)0.f, acc10 = (v4f)0.f, acc11 = (v4f)0.f;

#define LOADS_R(KQ, A0_, A1_, B0_, B1_) {                                     \
    int dxy_ = (KQ) >> 3, c32_ = (KQ) & 7;                                    \
    int dy_ = (dxy_ * 11) >> 5; int dx_ = dxy_ - dy_ * 3;                     \
    int ao_ = ((dy_ * 18 + dx_) * 256 + c32_ * 32) * 2; int bo_ = (KQ) * 64;  \
    A0_ = *(const v8h*)(abase[0] + ao_); A1_ = *(const v8h*)(abase[1] + ao_); \
    B0_ = *(const v8h*)(bbase[0] + bo_); B1_ = *(const v8h*)(bbase[1] + bo_); }

    v8h a0c, a1c, b0c, b1c, a0n, a1n, b0n, b1n;
    LOADS_R(0, a0c, a1c, b0c, b1c);
    LOADS_R(1, a0n, a1n, b0n, b1n);
    #pragma unroll
    for (int kq = 0; kq < KQN; ++kq) {
        v8h a0f, a1f, b0f, b1f;
        if (kq + 2 < KQN) LOADS_R(kq + 2, a0f, a1f, b0f, b1f);
        acc00 = __builtin_amdgcn_mfma_f32_16x16x32_f16(a0c, b0c, acc00, 0, 0, 0);
        acc01 = __builtin_amdgcn_mfma_f32_16x16x32_f16(a0c, b1c, acc01, 0, 0, 0);
        acc10 = __builtin_amdgcn_mfma_f32_16x16x32_f16(a1c, b0c, acc10, 0, 0, 0);
        acc11 = __builtin_amdgcn_mfma_f32_16x16x32_f16(a1c, b1c, acc11, 0, 0, 0);
        a0c = a0n; a1c = a1n; b0c = b0n; b1c = b1n;
        a0n = a0f; a1n = a1f; b0n = b0f; b1n = b1f;
    }
#undef LOADS_R

    // epilogue: quad-transpose (gate-lane <-> row-reg), + xg, cell update.
    v4f accA[2][2] = {{acc00, acc01}, {acc10, acc11}};
    const bool g0 = lane & 1, g1 = lane & 2;
    #pragma unroll
    for (int mi = 0; mi < 2; ++mi) {
        #pragma unroll
        for (int ni = 0; ni < 2; ++ni) {
            float V0 = accA[mi][ni][0], V1 = accA[mi][ni][1];
            float V2 = accA[mi][ni][2], V3 = accA[mi][ni][3];
            float x0 = __shfl_xor(V0, 1), x1 = __shfl_xor(V1, 1);
            float x2 = __shfl_xor(V2, 1), x3 = __shfl_xor(V3, 1);
            float a0 = g0 ? x1 : V0;
            float a1 = g0 ? V1 : x0;
            float a2 = g0 ? x3 : V2;
            float a3 = g0 ? V3 : x2;
            float s0 = __shfl_xor(a0, 2), s1 = __shfl_xor(a1, 2);
            float s2 = __shfl_xor(a2, 2), s3 = __shfl_xor(a3, 2);
            float Ti = g1 ? s2 : a0;   // gate i, row lane&3
            float Tf = g1 ? s3 : a1;   // gate f
            float Tc = g1 ? a2 : s0;   // gate c~
            float To = g1 ? a3 : s1;   // gate o

            int row = m0 + wr * 32 + mi * 16 + ((lane >> 4) << 2) + (lane & 3);
            int f4  = n0 + wc * 32 + ni * 16 + (lane & 12);
            int img = row >> 8, pix = row & 255, fch = f4 >> 2;
            long xrow = ((long)(img * TSTEPS + t) * HW + pix);
            const float4 xv = *(const float4*)&xg[xrow * COUT + f4];
            float pi = Ti + xv.x, pf = Tf + xv.y, pc = Tc + xv.z, po = To + xv.w;
            long cidx = (long)row * 256 + fch;
            float c = hsig(pf) * cbuf[cidx] + hsig(pi) * tanhf(pc);
            float h = hsig(po) * tanhf(c);
            cbuf[cidx] = c;
            hs[xrow * 256 + fch] = h;
            int yy = pix >> 4, xx = pix & 15;
            ph_out[(((long)img * 18 + yy + 1) * 18 + xx + 1) * 256 + fch] = f2h(h);
        }
    }
}

// ---------------------------------------------------------------------------
// weight prep: w (3,3,256,1024) fp32 -> wT (1024 n', 2304) fp16,
// n' = f*4 + g  (orig n = g*256 + f)
// ---------------------------------------------------------------------------
__global__ __launch_bounds__(256) void wprep_k(const float* __restrict__ w,
                                               u16* __restrict__ wT)
{
    int k0 = blockIdx.x * 32;
    int np = blockIdx.y * 256 + threadIdx.x;      // n' row
    int n  = (np & 3) * 256 + (np >> 2);          // original column
    u32 pk[16];
    #pragma unroll
    for (int kk = 0; kk < 32; kk += 2) {
        float a = w[(long)(k0 + kk) * COUT + n];
        float b = w[(long)(k0 + kk + 1) * COUT + n];
        pk[kk >> 1] = (u32)f2h(a) | ((u32)f2h(b) << 16);
    }
    uint4* dst = (uint4*)&wT[(long)np * KTOT + k0];
    dst[0] = make_uint4(pk[0], pk[1], pk[2], pk[3]);
    dst[1] = make_uint4(pk[4], pk[5], pk[6], pk[7]);
    dst[2] = make_uint4(pk[8], pk[9], pk[10], pk[11]);
    dst[3] = make_uint4(pk[12], pk[13], pk[14], pk[15]);
}

// ---------------------------------------------------------------------------
// convert input x (32,16,16,256) fp32 -> pad_x interior fp16
// ---------------------------------------------------------------------------
__global__ __launch_bounds__(256) void convert_x_k(const float* __restrict__ x,
                                                   u16* __restrict__ padx)
{
    int q = blockIdx.x * 256 + threadIdx.x;     // float4 index, 524288 total
    int e0 = q * 4;
    int f = e0 & 255, pix = (e0 >> 8) & 255, img = e0 >> 16;
    float4 v = ((const float4*)x)[q];
    int yy = pix >> 4, xx = pix & 15;
    long o = (((long)img * 18 + yy + 1) * 18 + xx + 1) * 256 + f;
    u32 lo = (u32)f2h(v.x) | ((u32)f2h(v.y) << 16);
    u32 hi = (u32)f2h(v.z) | ((u32)f2h(v.w) << 16);
    *(uint2*)&padx[o] = make_uint2(lo, hi);
}

// ---------------------------------------------------------------------------
// BatchNorm: deterministic two-stage stats + apply
// ---------------------------------------------------------------------------
__global__ __launch_bounds__(256) void bn_stats1_k(
    const float* __restrict__ x, float* __restrict__ partial)
{
    const int tid = threadIdx.x;
    const int blk = blockIdx.x;
    float s = 0.f, s2 = 0.f;
    const long base = (long)blk * 16 * 256;
    #pragma unroll
    for (int gi = 0; gi < 16; ++gi) {
        float v = x[base + gi * 256 + tid];
        s += v; s2 += v * v;
    }
    partial[blk * 512 + tid]       = s;
    partial[blk * 512 + 256 + tid] = s2;
}

__global__ __launch_bounds__(256) void bn_stats2_k(
    const float* __restrict__ partial, const float* __restrict__ gamma,
    const float* __restrict__ beta, float* __restrict__ stats)
{
    const int f = threadIdx.x;
    float s = 0.f, s2 = 0.f;
    for (int b = 0; b < 512; ++b) {
        s  += partial[b * 512 + f];
        s2 += partial[b * 512 + 256 + f];
    }
    const float inv_n = 1.f / 8192.f;
    float mu  = s * inv_n;
    float var = s2 * inv_n - mu * mu;
    float sc  = gamma[f] * rsqrtf(var + BN_EPS);
    stats[f]       = sc;
    stats[256 + f] = beta[f] - mu * sc;
}

// writes fp16 into pad_x interior (layers 0,1) or fp32 to d_out (layer 2)
__global__ __launch_bounds__(256) void bn_apply_k(
    const float* __restrict__ x, const float* __restrict__ stats,
    u16* __restrict__ padx, float* __restrict__ out)
{
    const int q = blockIdx.x * 256 + threadIdx.x;   // float4 index
    const int e0 = q * 4;
    const int f = e0 & 255, pix = (e0 >> 8) & 255, img = e0 >> 16;
    float4 v  = ((const float4*)x)[q];
    float4 sc = *(const float4*)(stats + f);
    float4 sh = *(const float4*)(stats + 256 + f);
    v.x = v.x * sc.x + sh.x;
    v.y = v.y * sc.y + sh.y;
    v.z = v.z * sc.z + sh.z;
    v.w = v.w * sc.w + sh.w;
    if (out) ((float4*)out)[q] = v;
    if (padx) {
        int yy = pix >> 4, xx = pix & 15;
        long o = (((long)img * 18 + yy + 1) * 18 + xx + 1) * 256 + f;
        u32 lo = (u32)f2h(v.x) | ((u32)f2h(v.y) << 16);
        u32 hi = (u32)f2h(v.z) | ((u32)f2h(v.w) << 16);
        *(uint2*)&padx[o] = make_uint2(lo, hi);
    }
}

// ---------------------------------------------------------------------------
extern "C" void kernel_launch(void* const* d_in, const int* in_sizes, int n_in,
                              void* d_out, int out_size, void* d_ws, size_t ws_size,
                              hipStream_t stream)
{
    const float* x0    = (const float*)d_in[0];
    const float* Wx[3] = {(const float*)d_in[1], (const float*)d_in[6],  (const float*)d_in[11]};
    const float* Wh[3] = {(const float*)d_in[2], (const float*)d_in[7],  (const float*)d_in[12]};
    const float* bb[3] = {(const float*)d_in[3], (const float*)d_in[8],  (const float*)d_in[13]};
    const float* gg[3] = {(const float*)d_in[4], (const float*)d_in[9],  (const float*)d_in[14]};
    const float* be[3] = {(const float*)d_in[5], (const float*)d_in[10], (const float*)d_in[15]};

    float* ws    = (float*)d_ws;
    float* xg    = ws;                    // 8,388,608 f32 (8192 x 1024, n' order)
    float* cbuf  = xg    + 8388608;       //   262,144
    float* hs    = cbuf  + 262144;        // 2,097,152
    float* part  = hs    + 2097152;       //   262,144
    float* stats = part  + 262144;        //       512
    u16*  pad_x  = (u16*)(stats + 512);   // 32*18*18*256 = 2,654,208 fp16
    u16*  pad_h  = pad_x + 2654208;       // 2 x 4*18*18*256 = 663,552 (ping-pong)
    u16*  wTx    = pad_h + 663552;        // 1024*2304 = 2,359,296
    u16*  wTh    = wTx   + 2359296;       //             2,359,296
    const long PHN = 331776;              // one pad_h buffer (u16 elems)
    // total ~60.1 MB

    hipMemsetAsync(pad_x, 0, 2654208 * sizeof(u16), stream);   // halo zeros
    hipLaunchKernelGGL(convert_x_k, dim3(2048), dim3(256), 0, stream, x0, pad_x);

    for (int l = 0; l < 3; ++l) {
        hipLaunchKernelGGL(wprep_k, dim3(72, 4), dim3(256), 0, stream, Wx[l], wTx);
        hipLaunchKernelGGL(wprep_k, dim3(72, 4), dim3(256), 0, stream, Wh[l], wTh);

        // input-to-gate conv for all 32 images (n'-order, bias folded)
        hipLaunchKernelGGL(conv_big_k, dim3(512), dim3(256), 0, stream,
            pad_x, wTx, bb[l], xg);

        hipMemsetAsync(pad_h, 0, 2 * PHN * sizeof(u16), stream);  // halos + h0
        hipMemsetAsync(cbuf, 0, 262144 * sizeof(float), stream);

        for (int t = 0; t < TSTEPS; ++t) {
            hipLaunchKernelGGL(rec_fused_k, dim3(256), dim3(256), 0, stream,
                pad_h + (t & 1) * PHN, wTh, xg, cbuf, hs,
                pad_h + ((t & 1) ^ 1) * PHN, t);
        }

        hipLaunchKernelGGL(bn_stats1_k, dim3(512), dim3(256), 0, stream, hs, part);
        hipLaunchKernelGGL(bn_stats2_k, dim3(1), dim3(256), 0, stream, part, gg[l], be[l], stats);
        hipLaunchKernelGGL(bn_apply_k, dim3(2048), dim3(256), 0, stream, hs, stats,
            (l < 2) ? pad_x : (u16*)nullptr, (l == 2) ? (float*)d_out : (float*)nullptr);
    }
}

// Round 6
// 587.227 us; speedup vs baseline: 1.9467x; 1.9467x over previous
//
#include <hip/hip_runtime.h>

// B=4, T=8, H=W=16, C=F=256, gates 4F=1024. K = 9*256 = 2304.
// Round 6: BK=64 (128B LDS rows -> bank-neutral, uniform slot swizzle
// g=(lane&7)^(row&7) on gl16 SOURCE + ds_read -> ~0 conflicts), stage-after-
// barrier pipelines (conv: depth-2 vmcnt(0); rec: depth-3 counted vmcnt(3)),
// rec back to LDS staging with 512 blocks (2/CU), conv_big XCD mapping
// (by-pair x bx-half) for L2 fit, xg stored fp16.
#define HW      256
#define COUT    1024
#define TSTEPS  8
#define BN_EPS  1e-3f
#define KTOT    2304

typedef unsigned short u16;
typedef unsigned int   u32;
typedef __attribute__((ext_vector_type(8))) _Float16 v8h;  // 8 x fp16
typedef __attribute__((ext_vector_type(4))) float v4f;

__device__ __forceinline__ u16 f2h(float x) {
    _Float16 h = (_Float16)x; return *(u16*)&h;
}
__device__ __forceinline__ float h2f(u16 u) {
    _Float16 h = *(_Float16*)&u; return (float)h;
}
__device__ __forceinline__ float hsig(float x) {
    return fminf(fmaxf(0.2f * x + 0.5f, 0.f), 1.f);
}

typedef __attribute__((address_space(1))) const unsigned int gas_u32;
typedef __attribute__((address_space(3))) unsigned int las_u32;
__device__ __forceinline__ void gl16(const void* g, void* l) {
    __builtin_amdgcn_global_load_lds((gas_u32*)g, (las_u32*)l, 16, 0, 0);
}

// ---------------------------------------------------------------------------
// Big input conv: M=8192, N'=1024 gate-interleaved, K=2304. BM=BN=128, BK=64,
// 4 waves (2x2), depth-2 stage-after-barrier pipeline, 64KB LDS (2 blk/CU).
// Grid 512: XCD gets (by-pair, bx-half) -> per-XCD L2 set ~3.7MB.
// ---------------------------------------------------------------------------
__global__ __launch_bounds__(256, 2) void conv_big_k(
    const u16* __restrict__ apad,     // (32,18,18,256) fp16 zero-padded
    const u16* __restrict__ wT,       // (1024 n', 2304) fp16
    const float* __restrict__ bias,   // (1024) original n order
    u16* __restrict__ out)            // (8192, 1024) fp16, n' order
{
    constexpr int KQ = 36;
    __shared__ u16 lds[2 * 16384];    // 2 bufs x 32KB (A 16KB + B 16KB)

    const int bid = blockIdx.x;
    const int xcd = bid & 7, idx = bid >> 3;
    const int by = (xcd >> 1) * 2 + (idx & 1);        // 0..7
    const int bx = (xcd & 1) * 32 + (idx >> 1);       // 0..63
    const int m0 = bx * 128, n0 = by * 128;
    const int tid = threadIdx.x, lane = tid & 63, w = tid >> 6;
    const int wr = w >> 1, wc = w & 1;
    const int lr = lane >> 3;             // staging row-in-8
    const int g  = (lane & 7) ^ lr;       // source granule (inverse swizzle)
    const int fr = lane & 15, kc = lane >> 4;

    const char* a_src[4];
    #pragma unroll
    for (int i = 0; i < 4; ++i) {
        int m = m0 + w * 32 + i * 8 + lr;
        int img = m >> 8, pix = m & 255, yy = pix >> 4, xx = pix & 15;
        a_src[i] = (const char*)apad + ((((long)img * 18 + yy) * 18 + xx) * 256 + g * 8) * 2;
    }
    const char* b_src[4];
    #pragma unroll
    for (int i = 0; i < 4; ++i) {
        int n = n0 + w * 32 + i * 8 + lr;
        b_src[i] = (const char*)wT + ((long)n * KTOT + g * 8) * 2;
    }

    // ds_read byte offsets (swizzled slot = granule ^ (row&7); rows bank-neutral)
    int aro[4][2], bro[4][2];
    #pragma unroll
    for (int mi = 0; mi < 4; ++mi) {
        int rl = wr * 64 + mi * 16 + fr;
        #pragma unroll
        for (int ks = 0; ks < 2; ++ks)
            aro[mi][ks] = rl * 128 + ((((ks << 2) | kc) ^ (fr & 7)) << 4);
    }
    #pragma unroll
    for (int ni = 0; ni < 4; ++ni) {
        int nr = wc * 64 + ni * 16 + fr;
        #pragma unroll
        for (int ks = 0; ks < 2; ++ks)
            bro[ni][ks] = 16384 + nr * 128 + ((((ks << 2) | kc) ^ (fr & 7)) << 4);
    }

    v4f acc[4][4];
    #pragma unroll
    for (int mi = 0; mi < 4; ++mi)
        #pragma unroll
        for (int ni = 0; ni < 4; ++ni) acc[mi][ni] = (v4f)0.f;

#define STAGE_B(J) { int j_ = (J); int dxy = j_ >> 2, c64 = j_ & 3;           \
    int dy = (dxy * 11) >> 5; int dx = dxy - dy * 3;                          \
    int aoff = ((dy * 18 + dx) * 256 + c64 * 64) * 2; int boff = j_ * 128;    \
    char* base = (char*)lds + (j_ & 1) * 32768;                               \
    _Pragma("unroll") for (int i = 0; i < 4; ++i)                             \
        gl16(a_src[i] + aoff, base + (w * 32 + i * 8) * 128);                 \
    _Pragma("unroll") for (int i = 0; i < 4; ++i)                             \
        gl16(b_src[i] + boff, base + 16384 + (w * 32 + i * 8) * 128); }

#define COMPUTE_B(J) { const char* base = (const char*)lds + ((J) & 1) * 32768; \
    v8h af[4][2], bf[4][2];                                                   \
    _Pragma("unroll") for (int mi = 0; mi < 4; ++mi)                          \
        _Pragma("unroll") for (int ks = 0; ks < 2; ++ks)                      \
            af[mi][ks] = *(const v8h*)(base + aro[mi][ks]);                   \
    _Pragma("unroll") for (int ni = 0; ni < 4; ++ni)                          \
        _Pragma("unroll") for (int ks = 0; ks < 2; ++ks)                      \
            bf[ni][ks] = *(const v8h*)(base + bro[ni][ks]);                   \
    __builtin_amdgcn_s_setprio(1);                                            \
    _Pragma("unroll") for (int ks = 0; ks < 2; ++ks)                          \
    _Pragma("unroll") for (int mi = 0; mi < 4; ++mi)                          \
    _Pragma("unroll") for (int ni = 0; ni < 4; ++ni)                          \
        acc[mi][ni] = __builtin_amdgcn_mfma_f32_16x16x32_f16(af[mi][ks], bf[ni][ks], acc[mi][ni], 0, 0, 0); \
    __builtin_amdgcn_s_setprio(0); }

    STAGE_B(0);
    for (int kq = 0; kq < KQ - 1; ++kq) {
        asm volatile("s_waitcnt vmcnt(0)" ::: "memory");
        __builtin_amdgcn_s_barrier();
        __builtin_amdgcn_sched_barrier(0);
        STAGE_B(kq + 1);
        COMPUTE_B(kq);
    }
    asm volatile("s_waitcnt vmcnt(0)" ::: "memory");
    __builtin_amdgcn_s_barrier();
    __builtin_amdgcn_sched_barrier(0);
    COMPUTE_B(KQ - 1);
#undef STAGE_B
#undef COMPUTE_B

    // epilogue: + bias (remapped n' -> n), store fp16 n'-order
    #pragma unroll
    for (int mi = 0; mi < 4; ++mi) {
        #pragma unroll
        for (int ni = 0; ni < 4; ++ni) {
            int mrow = m0 + wr * 64 + mi * 16 + ((lane >> 4) << 2);
            int ncol = n0 + wc * 64 + ni * 16 + fr;
            float b0 = bias[(ncol & 3) * 256 + (ncol >> 2)];
            #pragma unroll
            for (int r = 0; r < 4; ++r)
                out[(long)(mrow + r) * COUT + ncol] = f2h(acc[mi][ni][r] + b0);
        }
    }
}

// ---------------------------------------------------------------------------
// Recurrent conv + fused LSTM cell. M=1024, N'=1024, tile 32x64, BK=64,
// 512 blocks (2/CU), 4 waves (1x4), depth-3 counted-vmcnt pipeline (36KB LDS).
// ---------------------------------------------------------------------------
__global__ __launch_bounds__(256, 2) void rec_fused_k(
    const u16* __restrict__ ph_in,    // (4,18,18,256) fp16  h_{t-1}
    const u16* __restrict__ wT,       // (1024 n', 2304) fp16
    const u16* __restrict__ xg,       // (8192, 1024) fp16, n' order (incl bias)
    float* __restrict__ cbuf,         // (4,256,256)
    float* __restrict__ hs,           // (4,8,256,256)
    u16* __restrict__ ph_out,         // (4,18,18,256) fp16  h_t
    int t)
{
    constexpr int KQ = 36;
    __shared__ u16 lds[3 * 6144];     // 3 bufs x 12KB (A 4KB + B 8KB)

    const int bid = blockIdx.x;       // 512; n-slab pairs per XCD
    const int k8 = bid & 7, q = bid >> 3;
    const int by = k8 * 2 + (q >> 5), bx = q & 31;
    const int m0 = bx * 32, n0 = by * 64;
    const int tid = threadIdx.x, lane = tid & 63, wv = tid >> 6;
    const int lr = lane >> 3, g = (lane & 7) ^ lr;
    const int fr = lane & 15, kc = lane >> 4;

    const char* a_src;
    { int m = m0 + wv * 8 + lr;
      int img = m >> 8, pix = m & 255, yy = pix >> 4, xx = pix & 15;
      a_src = (const char*)ph_in + ((((long)img * 18 + yy) * 18 + xx) * 256 + g * 8) * 2; }
    const char* b_src[2];
    #pragma unroll
    for (int i = 0; i < 2; ++i) {
        int n = n0 + wv * 16 + i * 8 + lr;
        b_src[i] = (const char*)wT + ((long)n * KTOT + g * 8) * 2;
    }

    int aro[2][2], bro[2];
    #pragma unroll
    for (int mi = 0; mi < 2; ++mi)
        #pragma unroll
        for (int ks = 0; ks < 2; ++ks)
            aro[mi][ks] = (mi * 16 + fr) * 128 + ((((ks << 2) | kc) ^ (fr & 7)) << 4);
    #pragma unroll
    for (int ks = 0; ks < 2; ++ks)
        bro[ks] = 4096 + (wv * 16 + fr) * 128 + ((((ks << 2) | kc) ^ (fr & 7)) << 4);

    v4f acc0 = (v4f)0.f, acc1 = (v4f)0.f;

#define STAGE_R(J) { int j_ = (J); int dxy = j_ >> 2, c64 = j_ & 3;           \
    int dy = (dxy * 11) >> 5; int dx = dxy - dy * 3;                          \
    int aoff = ((dy * 18 + dx) * 256 + c64 * 64) * 2; int boff = j_ * 128;    \
    char* base = (char*)lds + (j_ % 3) * 12288;                               \
    gl16(a_src + aoff, base + (wv * 8) * 128);                                \
    gl16(b_src[0] + boff, base + 4096 + (wv * 16) * 128);                     \
    gl16(b_src[1] + boff, base + 4096 + (wv * 16 + 8) * 128); }

#define COMPUTE_R(J) { const char* base = (const char*)lds + ((J) % 3) * 12288; \
    v8h a00 = *(const v8h*)(base + aro[0][0]);                                \
    v8h a01 = *(const v8h*)(base + aro[0][1]);                                \
    v8h a10 = *(const v8h*)(base + aro[1][0]);                                \
    v8h a11 = *(const v8h*)(base + aro[1][1]);                                \
    v8h b0  = *(const v8h*)(base + bro[0]);                                   \
    v8h b1  = *(const v8h*)(base + bro[1]);                                   \
    __builtin_amdgcn_s_setprio(1);                                            \
    acc0 = __builtin_amdgcn_mfma_f32_16x16x32_f16(a00, b0, acc0, 0, 0, 0);    \
    acc1 = __builtin_amdgcn_mfma_f32_16x16x32_f16(a10, b0, acc1, 0, 0, 0);    \
    acc0 = __builtin_amdgcn_mfma_f32_16x16x32_f16(a01, b1, acc0, 0, 0, 0);    \
    acc1 = __builtin_amdgcn_mfma_f32_16x16x32_f16(a11, b1, acc1, 0, 0, 0);    \
    __builtin_amdgcn_s_setprio(0); }

    STAGE_R(0); STAGE_R(1);
    for (int kq = 0; kq < KQ - 2; ++kq) {
        asm volatile("s_waitcnt vmcnt(3)" ::: "memory");   // keep stage(kq+1) in flight
        __builtin_amdgcn_s_barrier();
        __builtin_amdgcn_sched_barrier(0);
        STAGE_R(kq + 2);
        COMPUTE_R(kq);
    }
    asm volatile("s_waitcnt vmcnt(3)" ::: "memory");
    __builtin_amdgcn_s_barrier();
    __builtin_amdgcn_sched_barrier(0);
    COMPUTE_R(KQ - 2);
    asm volatile("s_waitcnt vmcnt(0)" ::: "memory");
    __builtin_amdgcn_s_barrier();
    __builtin_amdgcn_sched_barrier(0);
    COMPUTE_R(KQ - 1);
#undef STAGE_R
#undef COMPUTE_R

    // epilogue: quad-transpose (gate-lane <-> row-reg), + xg(fp16), cell update.
    v4f accA[2] = {acc0, acc1};
    const bool gl0 = lane & 1, gl1 = lane & 2;
    #pragma unroll
    for (int mi = 0; mi < 2; ++mi) {
        float V0 = accA[mi][0], V1 = accA[mi][1];
        float V2 = accA[mi][2], V3 = accA[mi][3];
        float x0 = __shfl_xor(V0, 1), x1 = __shfl_xor(V1, 1);
        float x2 = __shfl_xor(V2, 1), x3 = __shfl_xor(V3, 1);
        float a0 = gl0 ? x1 : V0;
        float a1 = gl0 ? V1 : x0;
        float a2 = gl0 ? x3 : V2;
        float a3 = gl0 ? V3 : x2;
        float s0 = __shfl_xor(a0, 2), s1 = __shfl_xor(a1, 2);
        float s2 = __shfl_xor(a2, 2), s3 = __shfl_xor(a3, 2);
        float Ti = gl1 ? s2 : a0;   // gate i
        float Tf = gl1 ? s3 : a1;   // gate f
        float Tc = gl1 ? a2 : s0;   // gate c~
        float To = gl1 ? a3 : s1;   // gate o

        int row = m0 + mi * 16 + ((lane >> 4) << 2) + (lane & 3);
        int f4  = n0 + wv * 16 + (lane & 12);
        int img = row >> 8, pix = row & 255, fch = f4 >> 2;
        long xrow = ((long)(img * TSTEPS + t) * HW + pix);
        uint2 xb = *(const uint2*)&xg[xrow * COUT + f4];
        float pi = Ti + h2f((u16)(xb.x & 0xffff));
        float pf = Tf + h2f((u16)(xb.x >> 16));
        float pc = Tc + h2f((u16)(xb.y & 0xffff));
        float po = To + h2f((u16)(xb.y >> 16));
        long cidx = (long)row * 256 + fch;
        float c = hsig(pf) * cbuf[cidx] + hsig(pi) * tanhf(pc);
        float h = hsig(po) * tanhf(c);
        cbuf[cidx] = c;
        hs[xrow * 256 + fch] = h;
        int yy = pix >> 4, xx = pix & 15;
        ph_out[(((long)img * 18 + yy + 1) * 18 + xx + 1) * 256 + fch] = f2h(h);
    }
}

// ---------------------------------------------------------------------------
// weight prep: w (3,3,256,1024) fp32 -> wT (1024 n', 2304) fp16, n' = f*4+g
// ---------------------------------------------------------------------------
__global__ __launch_bounds__(256) void wprep_k(const float* __restrict__ w,
                                               u16* __restrict__ wT)
{
    int k0 = blockIdx.x * 32;
    int np = blockIdx.y * 256 + threadIdx.x;      // n' row
    int n  = (np & 3) * 256 + (np >> 2);          // original column
    u32 pk[16];
    #pragma unroll
    for (int kk = 0; kk < 32; kk += 2) {
        float a = w[(long)(k0 + kk) * COUT + n];
        float b = w[(long)(k0 + kk + 1) * COUT + n];
        pk[kk >> 1] = (u32)f2h(a) | ((u32)f2h(b) << 16);
    }
    uint4* dst = (uint4*)&wT[(long)np * KTOT + k0];
    dst[0] = make_uint4(pk[0], pk[1], pk[2], pk[3]);
    dst[1] = make_uint4(pk[4], pk[5], pk[6], pk[7]);
    dst[2] = make_uint4(pk[8], pk[9], pk[10], pk[11]);
    dst[3] = make_uint4(pk[12], pk[13], pk[14], pk[15]);
}

// ---------------------------------------------------------------------------
// convert input x (32,16,16,256) fp32 -> pad_x interior fp16
// ---------------------------------------------------------------------------
__global__ __launch_bounds__(256) void convert_x_k(const float* __restrict__ x,
                                                   u16* __restrict__ padx)
{
    int q = blockIdx.x * 256 + threadIdx.x;     // float4 index
    int e0 = q * 4;
    int f = e0 & 255, pix = (e0 >> 8) & 255, img = e0 >> 16;
    float4 v = ((const float4*)x)[q];
    int yy = pix >> 4, xx = pix & 15;
    long o = (((long)img * 18 + yy + 1) * 18 + xx + 1) * 256 + f;
    u32 lo = (u32)f2h(v.x) | ((u32)f2h(v.y) << 16);
    u32 hi = (u32)f2h(v.z) | ((u32)f2h(v.w) << 16);
    *(uint2*)&padx[o] = make_uint2(lo, hi);
}

// ---------------------------------------------------------------------------
// BatchNorm: deterministic two-stage stats + apply
// ---------------------------------------------------------------------------
__global__ __launch_bounds__(256) void bn_stats1_k(
    const float* __restrict__ x, float* __restrict__ partial)
{
    const int tid = threadIdx.x;
    const int blk = blockIdx.x;
    float s = 0.f, s2 = 0.f;
    const long base = (long)blk * 16 * 256;
    #pragma unroll
    for (int gi = 0; gi < 16; ++gi) {
        float v = x[base + gi * 256 + tid];
        s += v; s2 += v * v;
    }
    partial[blk * 512 + tid]       = s;
    partial[blk * 512 + 256 + tid] = s2;
}

__global__ __launch_bounds__(256) void bn_stats2_k(
    const float* __restrict__ partial, const float* __restrict__ gamma,
    const float* __restrict__ beta, float* __restrict__ stats)
{
    const int f = threadIdx.x;
    float s = 0.f, s2 = 0.f;
    for (int b = 0; b < 512; ++b) {
        s  += partial[b * 512 + f];
        s2 += partial[b * 512 + 256 + f];
    }
    const float inv_n = 1.f / 8192.f;
    float mu  = s * inv_n;
    float var = s2 * inv_n - mu * mu;
    float sc  = gamma[f] * rsqrtf(var + BN_EPS);
    stats[f]       = sc;
    stats[256 + f] = beta[f] - mu * sc;
}

__global__ __launch_bounds__(256) void bn_apply_k(
    const float* __restrict__ x, const float* __restrict__ stats,
    u16* __restrict__ padx, float* __restrict__ out)
{
    const int q = blockIdx.x * 256 + threadIdx.x;   // float4 index
    const int e0 = q * 4;
    const int f = e0 & 255, pix = (e0 >> 8) & 255, img = e0 >> 16;
    float4 v  = ((const float4*)x)[q];
    float4 sc = *(const float4*)(stats + f);
    float4 sh = *(const float4*)(stats + 256 + f);
    v.x = v.x * sc.x + sh.x;
    v.y = v.y * sc.y + sh.y;
    v.z = v.z * sc.z + sh.z;
    v.w = v.w * sc.w + sh.w;
    if (out) ((float4*)out)[q] = v;
    if (padx) {
        int yy = pix >> 4, xx = pix & 15;
        long o = (((long)img * 18 + yy + 1) * 18 + xx + 1) * 256 + f;
        u32 lo = (u32)f2h(v.x) | ((u32)f2h(v.y) << 16);
        u32 hi = (u32)f2h(v.z) | ((u32)f2h(v.w) << 16);
        *(uint2*)&padx[o] = make_uint2(lo, hi);
    }
}

// ---------------------------------------------------------------------------
extern "C" void kernel_launch(void* const* d_in, const int* in_sizes, int n_in,
                              void* d_out, int out_size, void* d_ws, size_t ws_size,
                              hipStream_t stream)
{
    const float* x0    = (const float*)d_in[0];
    const float* Wx[3] = {(const float*)d_in[1], (const float*)d_in[6],  (const float*)d_in[11]};
    const float* Wh[3] = {(const float*)d_in[2], (const float*)d_in[7],  (const float*)d_in[12]};
    const float* bb[3] = {(const float*)d_in[3], (const float*)d_in[8],  (const float*)d_in[13]};
    const float* gg[3] = {(const float*)d_in[4], (const float*)d_in[9],  (const float*)d_in[14]};
    const float* be[3] = {(const float*)d_in[5], (const float*)d_in[10], (const float*)d_in[15]};

    float* ws    = (float*)d_ws;
    u16*  xg     = (u16*)ws;              // 8,388,608 u16 (8192 x 1024 fp16, n')
    float* cbuf  = ws   + 4194304;        //   262,144 f32
    float* hs    = cbuf + 262144;         // 2,097,152 f32
    float* part  = hs   + 2097152;        //   262,144
    float* stats = part + 262144;         //       512
    u16*  pad_x  = (u16*)(stats + 512);   // 32*18*18*256 = 2,654,208 fp16
    u16*  pad_h  = pad_x + 2654208;       // 2 x 331,776 (ping-pong)
    u16*  wTx    = pad_h + 663552;        // 1024*2304
    u16*  wTh    = wTx   + 2359296;
    const long PHN = 331776;

    hipMemsetAsync(pad_x, 0, 2654208 * sizeof(u16), stream);   // halo zeros
    hipLaunchKernelGGL(convert_x_k, dim3(2048), dim3(256), 0, stream, x0, pad_x);

    for (int l = 0; l < 3; ++l) {
        hipLaunchKernelGGL(wprep_k, dim3(72, 4), dim3(256), 0, stream, Wx[l], wTx);
        hipLaunchKernelGGL(wprep_k, dim3(72, 4), dim3(256), 0, stream, Wh[l], wTh);

        hipLaunchKernelGGL(conv_big_k, dim3(512), dim3(256), 0, stream,
            pad_x, wTx, bb[l], xg);

        hipMemsetAsync(pad_h, 0, 2 * PHN * sizeof(u16), stream);  // halos + h0
        hipMemsetAsync(cbuf, 0, 262144 * sizeof(float), stream);

        for (int t = 0; t < TSTEPS; ++t) {
            hipLaunchKernelGGL(rec_fused_k, dim3(512), dim3(256), 0, stream,
                pad_h + (t & 1) * PHN, wTh, xg, cbuf, hs,
                pad_h + ((t & 1) ^ 1) * PHN, t);
        }

        hipLaunchKernelGGL(bn_stats1_k, dim3(512), dim3(256), 0, stream, hs, part);
        hipLaunchKernelGGL(bn_stats2_k, dim3(1), dim3(256), 0, stream, part, gg[l], be[l], stats);
        hipLaunchKernelGGL(bn_apply_k, dim3(2048), dim3(256), 0, stream, hs, stats,
            (l < 2) ? pad_x : (u16*)nullptr, (l == 2) ? (float*)d_out : (float*)nullptr);
    }
}

// Round 7
// 554.209 us; speedup vs baseline: 2.0627x; 1.0596x over previous
//
#include <hip/hip_runtime.h>

// B=4, T=8, H=W=16, C=F=256, gates 4F=1024. K = 9*256 = 2304.
// Round 7: rec conv operand split — B (Wh) pre-packed in MFMA-fragment
// order and read per-lane-coalesced from L2 straight into VGPRs (no LDS);
// A (h) staged via gl16+LDS depth-3 with uniform counted vmcnt(2).
// t=0 recurrence replaced by gates-only kernel (h0=0). BN stats parallelized.
#define HW      256
#define COUT    1024
#define TSTEPS  8
#define BN_EPS  1e-3f
#define KTOT    2304

typedef unsigned short u16;
typedef unsigned int   u32;
typedef __attribute__((ext_vector_type(8))) _Float16 v8h;  // 8 x fp16
typedef __attribute__((ext_vector_type(4))) float v4f;

__device__ __forceinline__ u16 f2h(float x) {
    _Float16 h = (_Float16)x; return *(u16*)&h;
}
__device__ __forceinline__ float h2f(u16 u) {
    _Float16 h = *(_Float16*)&u; return (float)h;
}
__device__ __forceinline__ float hsig(float x) {
    return fminf(fmaxf(0.2f * x + 0.5f, 0.f), 1.f);
}

typedef __attribute__((address_space(1))) const unsigned int gas_u32;
typedef __attribute__((address_space(3))) unsigned int las_u32;
__device__ __forceinline__ void gl16(const void* g, void* l) {
    __builtin_amdgcn_global_load_lds((gas_u32*)g, (las_u32*)l, 16, 0, 0);
}

// ---------------------------------------------------------------------------
// Big input conv (unchanged from round 6): M=8192, N'=1024, BM=BN=128, BK=64,
// 4 waves (2x2), depth-2 stage-after-barrier, slot-swizzled LDS, 2 blk/CU.
// ---------------------------------------------------------------------------
__global__ __launch_bounds__(256, 2) void conv_big_k(
    const u16* __restrict__ apad,     // (32,18,18,256) fp16 zero-padded
    const u16* __restrict__ wT,       // (1024 n', 2304) fp16
    const float* __restrict__ bias,   // (1024) original n order
    u16* __restrict__ out)            // (8192, 1024) fp16, n' order
{
    constexpr int KQ = 36;
    __shared__ u16 lds[2 * 16384];

    const int bid = blockIdx.x;
    const int xcd = bid & 7, idx = bid >> 3;
    const int by = (xcd >> 1) * 2 + (idx & 1);
    const int bx = (xcd & 1) * 32 + (idx >> 1);
    const int m0 = bx * 128, n0 = by * 128;
    const int tid = threadIdx.x, lane = tid & 63, w = tid >> 6;
    const int wr = w >> 1, wc = w & 1;
    const int lr = lane >> 3;
    const int g  = (lane & 7) ^ lr;
    const int fr = lane & 15, kc = lane >> 4;

    const char* a_src[4];
    #pragma unroll
    for (int i = 0; i < 4; ++i) {
        int m = m0 + w * 32 + i * 8 + lr;
        int img = m >> 8, pix = m & 255, yy = pix >> 4, xx = pix & 15;
        a_src[i] = (const char*)apad + ((((long)img * 18 + yy) * 18 + xx) * 256 + g * 8) * 2;
    }
    const char* b_src[4];
    #pragma unroll
    for (int i = 0; i < 4; ++i) {
        int n = n0 + w * 32 + i * 8 + lr;
        b_src[i] = (const char*)wT + ((long)n * KTOT + g * 8) * 2;
    }

    int aro[4][2], bro[4][2];
    #pragma unroll
    for (int mi = 0; mi < 4; ++mi) {
        int rl = wr * 64 + mi * 16 + fr;
        #pragma unroll
        for (int ks = 0; ks < 2; ++ks)
            aro[mi][ks] = rl * 128 + ((((ks << 2) | kc) ^ (fr & 7)) << 4);
    }
    #pragma unroll
    for (int ni = 0; ni < 4; ++ni) {
        int nr = wc * 64 + ni * 16 + fr;
        #pragma unroll
        for (int ks = 0; ks < 2; ++ks)
            bro[ni][ks] = 16384 + nr * 128 + ((((ks << 2) | kc) ^ (fr & 7)) << 4);
    }

    v4f acc[4][4];
    #pragma unroll
    for (int mi = 0; mi < 4; ++mi)
        #pragma unroll
        for (int ni = 0; ni < 4; ++ni) acc[mi][ni] = (v4f)0.f;

#define STAGE_B(J) { int j_ = (J); int dxy = j_ >> 2, c64 = j_ & 3;           \
    int dy = (dxy * 11) >> 5; int dx = dxy - dy * 3;                          \
    int aoff = ((dy * 18 + dx) * 256 + c64 * 64) * 2; int boff = j_ * 128;    \
    char* base = (char*)lds + (j_ & 1) * 32768;                               \
    _Pragma("unroll") for (int i = 0; i < 4; ++i)                             \
        gl16(a_src[i] + aoff, base + (w * 32 + i * 8) * 128);                 \
    _Pragma("unroll") for (int i = 0; i < 4; ++i)                             \
        gl16(b_src[i] + boff, base + 16384 + (w * 32 + i * 8) * 128); }

#define COMPUTE_B(J) { const char* base = (const char*)lds + ((J) & 1) * 32768; \
    v8h af[4][2], bf[4][2];                                                   \
    _Pragma("unroll") for (int mi = 0; mi < 4; ++mi)                          \
        _Pragma("unroll") for (int ks = 0; ks < 2; ++ks)                      \
            af[mi][ks] = *(const v8h*)(base + aro[mi][ks]);                   \
    _Pragma("unroll") for (int ni = 0; ni < 4; ++ni)                          \
        _Pragma("unroll") for (int ks = 0; ks < 2; ++ks)                      \
            bf[ni][ks] = *(const v8h*)(base + bro[ni][ks]);                   \
    __builtin_amdgcn_s_setprio(1);                                            \
    _Pragma("unroll") for (int ks = 0; ks < 2; ++ks)                          \
    _Pragma("unroll") for (int mi = 0; mi < 4; ++mi)                          \
    _Pragma("unroll") for (int ni = 0; ni < 4; ++ni)                          \
        acc[mi][ni] = __builtin_amdgcn_mfma_f32_16x16x32_f16(af[mi][ks], bf[ni][ks], acc[mi][ni], 0, 0, 0); \
    __builtin_amdgcn_s_setprio(0); }

    STAGE_B(0);
    for (int kq = 0; kq < KQ - 1; ++kq) {
        asm volatile("s_waitcnt vmcnt(0)" ::: "memory");
        __builtin_amdgcn_s_barrier();
        __builtin_amdgcn_sched_barrier(0);
        STAGE_B(kq + 1);
        COMPUTE_B(kq);
    }
    asm volatile("s_waitcnt vmcnt(0)" ::: "memory");
    __builtin_amdgcn_s_barrier();
    __builtin_amdgcn_sched_barrier(0);
    COMPUTE_B(KQ - 1);
#undef STAGE_B
#undef COMPUTE_B

    #pragma unroll
    for (int mi = 0; mi < 4; ++mi) {
        #pragma unroll
        for (int ni = 0; ni < 4; ++ni) {
            int mrow = m0 + wr * 64 + mi * 16 + ((lane >> 4) << 2);
            int ncol = n0 + wc * 64 + ni * 16 + fr;
            float b0 = bias[(ncol & 3) * 256 + (ncol >> 2)];
            #pragma unroll
            for (int r = 0; r < 4; ++r)
                out[(long)(mrow + r) * COUT + ncol] = f2h(acc[mi][ni][r] + b0);
        }
    }
}

// ---------------------------------------------------------------------------
// Recurrent conv + fused LSTM cell, v3: 64x64 tile, 256 blocks (1/CU),
// 4 waves of 64m x 16n. B read fragment-packed from L2 into VGPRs (no LDS);
// A staged gl16->LDS depth-3; uniform counted vmcnt(2).
// ---------------------------------------------------------------------------
__global__ __launch_bounds__(256) void rec_fused_k(
    const u16* __restrict__ ph_in,    // (4,18,18,256) fp16  h_{t-1}
    const u16* __restrict__ wTf,      // frag-packed Wh: (64 nf, 72 kq, 512)
    const u16* __restrict__ xg,       // (8192, 1024) fp16, n' order (incl bias)
    float* __restrict__ cbuf,         // (4,256,256)
    float* __restrict__ hs,           // (4,8,256,256)
    u16* __restrict__ ph_out,         // (4,18,18,256) fp16  h_t
    int t)
{
    __shared__ u16 lds[3 * 4096];     // 3 bufs x 8KB (A only)

    const int bid = blockIdx.x;       // 256: by-pairs per XCD (bijective)
    const int by = (bid & 7) * 2 + ((bid >> 3) & 1);   // 0..15
    const int bx = bid >> 4;                           // 0..15
    const int m0 = bx * 64, n0 = by * 64;
    const int tid = threadIdx.x, lane = tid & 63, w = tid >> 6;
    const int lr = lane >> 3, g = (lane & 7) ^ lr;
    const int fr = lane & 15, kc = lane >> 4;

    const char* a_src[2];
    #pragma unroll
    for (int i = 0; i < 2; ++i) {
        int m = m0 + w * 16 + i * 8 + lr;
        int img = m >> 8, pix = m & 255, yy = pix >> 4, xx = pix & 15;
        a_src[i] = (const char*)ph_in + ((((long)img * 18 + yy) * 18 + xx) * 256 + g * 8) * 2;
    }
    // B fragment base: wave owns nf = by*4 + w; lane's 16B at +lane*16
    const char* b_base = (const char*)wTf + ((long)(by * 4 + w) * 72) * 1024 + lane * 16;

    int aro[4][2];
    #pragma unroll
    for (int mi = 0; mi < 4; ++mi)
        #pragma unroll
        for (int ks = 0; ks < 2; ++ks)
            aro[mi][ks] = (mi * 16 + fr) * 128 + ((((ks << 2) | kc) ^ (fr & 7)) << 4);

    v4f acc0 = (v4f)0.f, acc1 = (v4f)0.f, acc2 = (v4f)0.f, acc3 = (v4f)0.f;
    v8h b0x, b0y, b1x, b1y;

#define STAGE_A(J) { int j_ = (J); int dxy = j_ >> 2, c64 = j_ & 3;           \
    int dy = (dxy * 11) >> 5; int dx = dxy - dy * 3;                          \
    int aoff = ((dy * 18 + dx) * 256 + c64 * 64) * 2;                         \
    char* dst = (char*)lds + (j_ % 3) * 8192 + (w * 16) * 128;                \
    gl16(a_src[0] + aoff, dst); gl16(a_src[1] + aoff, dst + 1024); }

#define LDB(J, RX, RY) { RX = *(const v8h*)(b_base + (2 * (J)) * 1024);       \
                         RY = *(const v8h*)(b_base + (2 * (J) + 1) * 1024); }

#define COMPUTE(J, RX, RY) { const char* base = (const char*)lds + ((J) % 3) * 8192; \
    v8h af0 = *(const v8h*)(base + aro[0][0]);                                \
    v8h af1 = *(const v8h*)(base + aro[1][0]);                                \
    v8h af2 = *(const v8h*)(base + aro[2][0]);                                \
    v8h af3 = *(const v8h*)(base + aro[3][0]);                                \
    v8h ag0 = *(const v8h*)(base + aro[0][1]);                                \
    v8h ag1 = *(const v8h*)(base + aro[1][1]);                                \
    v8h ag2 = *(const v8h*)(base + aro[2][1]);                                \
    v8h ag3 = *(const v8h*)(base + aro[3][1]);                                \
    __builtin_amdgcn_s_setprio(1);                                            \
    acc0 = __builtin_amdgcn_mfma_f32_16x16x32_f16(af0, RX, acc0, 0, 0, 0);    \
    acc1 = __builtin_amdgcn_mfma_f32_16x16x32_f16(af1, RX, acc1, 0, 0, 0);    \
    acc2 = __builtin_amdgcn_mfma_f32_16x16x32_f16(af2, RX, acc2, 0, 0, 0);    \
    acc3 = __builtin_amdgcn_mfma_f32_16x16x32_f16(af3, RX, acc3, 0, 0, 0);    \
    acc0 = __builtin_amdgcn_mfma_f32_16x16x32_f16(ag0, RY, acc0, 0, 0, 0);    \
    acc1 = __builtin_amdgcn_mfma_f32_16x16x32_f16(ag1, RY, acc1, 0, 0, 0);    \
    acc2 = __builtin_amdgcn_mfma_f32_16x16x32_f16(ag2, RY, acc2, 0, 0, 0);    \
    acc3 = __builtin_amdgcn_mfma_f32_16x16x32_f16(ag3, RY, acc3, 0, 0, 0);    \
    __builtin_amdgcn_s_setprio(0); }

    // prologue: issue order [A0, B0, A1] so vmcnt(2) leaves exactly the next A
    STAGE_A(0); LDB(0, b0x, b0y); STAGE_A(1);
    for (int j = 0; j < 17; ++j) {
        int kq = 2 * j;
        asm volatile("s_waitcnt vmcnt(2)" ::: "memory");   // A(kq),B(kq) done; A(kq+1) in flight
        __builtin_amdgcn_s_barrier();
        __builtin_amdgcn_sched_barrier(0);
        LDB(kq + 1, b1x, b1y); STAGE_A(kq + 2);
        COMPUTE(kq, b0x, b0y);
        asm volatile("s_waitcnt vmcnt(2)" ::: "memory");
        __builtin_amdgcn_s_barrier();
        __builtin_amdgcn_sched_barrier(0);
        LDB(kq + 2, b0x, b0y); STAGE_A(kq + 3);
        COMPUTE(kq + 1, b1x, b1y);
    }
    // kq = 34, 35 (peeled tail)
    asm volatile("s_waitcnt vmcnt(2)" ::: "memory");
    __builtin_amdgcn_s_barrier();
    __builtin_amdgcn_sched_barrier(0);
    LDB(35, b1x, b1y);
    COMPUTE(34, b0x, b0y);
    asm volatile("s_waitcnt vmcnt(0)" ::: "memory");
    __builtin_amdgcn_s_barrier();
    __builtin_amdgcn_sched_barrier(0);
    COMPUTE(35, b1x, b1y);
#undef STAGE_A
#undef LDB
#undef COMPUTE

    // epilogue: quad-transpose (gate-lane <-> row-reg), + xg(fp16), cell update.
    v4f accA[4] = {acc0, acc1, acc2, acc3};
    const bool gl0 = lane & 1, gl1 = lane & 2;
    #pragma unroll
    for (int mi = 0; mi < 4; ++mi) {
        float V0 = accA[mi][0], V1 = accA[mi][1];
        float V2 = accA[mi][2], V3 = accA[mi][3];
        float x0 = __shfl_xor(V0, 1), x1 = __shfl_xor(V1, 1);
        float x2 = __shfl_xor(V2, 1), x3 = __shfl_xor(V3, 1);
        float a0 = gl0 ? x1 : V0;
        float a1 = gl0 ? V1 : x0;
        float a2 = gl0 ? x3 : V2;
        float a3 = gl0 ? V3 : x2;
        float s0 = __shfl_xor(a0, 2), s1 = __shfl_xor(a1, 2);
        float s2 = __shfl_xor(a2, 2), s3 = __shfl_xor(a3, 2);
        float Ti = gl1 ? s2 : a0;
        float Tf = gl1 ? s3 : a1;
        float Tc = gl1 ? a2 : s0;
        float To = gl1 ? a3 : s1;

        int row = m0 + mi * 16 + ((lane >> 4) << 2) + (lane & 3);
        int f4  = n0 + w * 16 + (lane & 12);
        int img = row >> 8, pix = row & 255, fch = f4 >> 2;
        long xrow = ((long)(img * TSTEPS + t) * HW + pix);
        uint2 xb = *(const uint2*)&xg[xrow * COUT + f4];
        float pi = Ti + h2f((u16)(xb.x & 0xffff));
        float pf = Tf + h2f((u16)(xb.x >> 16));
        float pc = Tc + h2f((u16)(xb.y & 0xffff));
        float po = To + h2f((u16)(xb.y >> 16));
        long cidx = (long)row * 256 + fch;
        float c = hsig(pf) * cbuf[cidx] + hsig(pi) * tanhf(pc);
        float h = hsig(po) * tanhf(c);
        cbuf[cidx] = c;
        hs[xrow * 256 + fch] = h;
        int yy = pix >> 4, xx = pix & 15;
        ph_out[(((long)img * 18 + yy + 1) * 18 + xx + 1) * 256 + fch] = f2h(h);
    }
}

// ---------------------------------------------------------------------------
// t=0 cell: h0=0 -> gates = xg only (no conv). Writes cbuf/hs/ph_out.
// ---------------------------------------------------------------------------
__global__ __launch_bounds__(256) void gates0_k(
    const u16* __restrict__ xg, float* __restrict__ cbuf,
    float* __restrict__ hs, u16* __restrict__ ph_out)
{
    int idx = blockIdx.x * 256 + threadIdx.x;     // 0..262143
    int fch = idx & 255, row = idx >> 8;
    int img = row >> 8, pix = row & 255;
    long xrow = (long)(img * TSTEPS) * HW + pix;
    uint2 xb = *(const uint2*)&xg[xrow * COUT + fch * 4];
    float pi = h2f((u16)(xb.x & 0xffff));
    float pc = h2f((u16)(xb.y & 0xffff));
    float po = h2f((u16)(xb.y >> 16));
    float c = hsig(pi) * tanhf(pc);
    float h = hsig(po) * tanhf(c);
    cbuf[(long)row * 256 + fch] = c;
    hs[xrow * 256 + fch] = h;
    int yy = pix >> 4, xx = pix & 15;
    ph_out[(((long)img * 18 + yy + 1) * 18 + xx + 1) * 256 + fch] = f2h(h);
}

// ---------------------------------------------------------------------------
// weight preps
// ---------------------------------------------------------------------------
__global__ __launch_bounds__(256) void wprep_k(const float* __restrict__ w,
                                               u16* __restrict__ wT)
{
    int k0 = blockIdx.x * 32;
    int np = blockIdx.y * 256 + threadIdx.x;      // n' row
    int n  = (np & 3) * 256 + (np >> 2);
    u32 pk[16];
    #pragma unroll
    for (int kk = 0; kk < 32; kk += 2) {
        float a = w[(long)(k0 + kk) * COUT + n];
        float b = w[(long)(k0 + kk + 1) * COUT + n];
        pk[kk >> 1] = (u32)f2h(a) | ((u32)f2h(b) << 16);
    }
    uint4* dst = (uint4*)&wT[(long)np * KTOT + k0];
    dst[0] = make_uint4(pk[0], pk[1], pk[2], pk[3]);
    dst[1] = make_uint4(pk[4], pk[5], pk[6], pk[7]);
    dst[2] = make_uint4(pk[8], pk[9], pk[10], pk[11]);
    dst[3] = make_uint4(pk[12], pk[13], pk[14], pk[15]);
}

// fragment-packed prep: wTf[((nf*72)+kq)*512 + l*8 + e] = Wh[k][n],
// n' = nf*16 + (l&15), k = kq*32 + (l>>4)*8 + e, n = (n'&3)*256 + (n'>>2)
__global__ __launch_bounds__(256) void wprep_frag_k(const float* __restrict__ w,
                                                    u16* __restrict__ wTf)
{
    int kq = blockIdx.x;                       // 0..71
    int nf = blockIdx.y * 4 + (threadIdx.x >> 6);
    int l  = threadIdx.x & 63;
    int np = nf * 16 + (l & 15);
    int n  = (np & 3) * 256 + (np >> 2);
    int k0 = kq * 32 + (l >> 4) * 8;
    u32 pk[4];
    #pragma unroll
    for (int e = 0; e < 8; e += 2) {
        float a = w[(long)(k0 + e) * COUT + n];
        float b = w[(long)(k0 + e + 1) * COUT + n];
        pk[e >> 1] = (u32)f2h(a) | ((u32)f2h(b) << 16);
    }
    *(uint4*)&wTf[((long)(nf * 72) + kq) * 512 + l * 8] =
        make_uint4(pk[0], pk[1], pk[2], pk[3]);
}

// ---------------------------------------------------------------------------
// convert input x (32,16,16,256) fp32 -> pad_x interior fp16
// ---------------------------------------------------------------------------
__global__ __launch_bounds__(256) void convert_x_k(const float* __restrict__ x,
                                                   u16* __restrict__ padx)
{
    int q = blockIdx.x * 256 + threadIdx.x;
    int e0 = q * 4;
    int f = e0 & 255, pix = (e0 >> 8) & 255, img = e0 >> 16;
    float4 v = ((const float4*)x)[q];
    int yy = pix >> 4, xx = pix & 15;
    long o = (((long)img * 18 + yy + 1) * 18 + xx + 1) * 256 + f;
    u32 lo = (u32)f2h(v.x) | ((u32)f2h(v.y) << 16);
    u32 hi = (u32)f2h(v.z) | ((u32)f2h(v.w) << 16);
    *(uint2*)&padx[o] = make_uint2(lo, hi);
}

// ---------------------------------------------------------------------------
// BatchNorm: deterministic two-stage stats + apply
// ---------------------------------------------------------------------------
__global__ __launch_bounds__(256) void bn_stats1_k(
    const float* __restrict__ x, float* __restrict__ partial)
{
    const int tid = threadIdx.x;
    const int blk = blockIdx.x;                // 64 blocks
    float s = 0.f, s2 = 0.f;
    const long base = (long)blk * 128 * 256;
    #pragma unroll 8
    for (int gi = 0; gi < 128; ++gi) {
        float v = x[base + gi * 256 + tid];
        s += v; s2 += v * v;
    }
    partial[blk * 512 + tid]       = s;
    partial[blk * 512 + 256 + tid] = s2;
}

__global__ __launch_bounds__(256) void bn_stats2_k(
    const float* __restrict__ partial, const float* __restrict__ gamma,
    const float* __restrict__ beta, float* __restrict__ stats)
{
    const int f = threadIdx.x;
    float s = 0.f, s2 = 0.f;
    #pragma unroll 8
    for (int b = 0; b < 64; ++b) {
        s  += partial[b * 512 + f];
        s2 += partial[b * 512 + 256 + f];
    }
    const float inv_n = 1.f / 8192.f;
    float mu  = s * inv_n;
    float var = s2 * inv_n - mu * mu;
    float sc  = gamma[f] * rsqrtf(var + BN_EPS);
    stats[f]       = sc;
    stats[256 + f] = beta[f] - mu * sc;
}

__global__ __launch_bounds__(256) void bn_apply_k(
    const float* __restrict__ x, const float* __restrict__ stats,
    u16* __restrict__ padx, float* __restrict__ out)
{
    const int q = blockIdx.x * 256 + threadIdx.x;
    const int e0 = q * 4;
    const int f = e0 & 255, pix = (e0 >> 8) & 255, img = e0 >> 16;
    float4 v  = ((const float4*)x)[q];
    float4 sc = *(const float4*)(stats + f);
    float4 sh = *(const float4*)(stats + 256 + f);
    v.x = v.x * sc.x + sh.x;
    v.y = v.y * sc.y + sh.y;
    v.z = v.z * sc.z + sh.z;
    v.w = v.w * sc.w + sh.w;
    if (out) ((float4*)out)[q] = v;
    if (padx) {
        int yy = pix >> 4, xx = pix & 15;
        long o = (((long)img * 18 + yy + 1) * 18 + xx + 1) * 256 + f;
        u32 lo = (u32)f2h(v.x) | ((u32)f2h(v.y) << 16);
        u32 hi = (u32)f2h(v.z) | ((u32)f2h(v.w) << 16);
        *(uint2*)&padx[o] = make_uint2(lo, hi);
    }
}

// ---------------------------------------------------------------------------
extern "C" void kernel_launch(void* const* d_in, const int* in_sizes, int n_in,
                              void* d_out, int out_size, void* d_ws, size_t ws_size,
                              hipStream_t stream)
{
    const float* x0    = (const float*)d_in[0];
    const float* Wx[3] = {(const float*)d_in[1], (const float*)d_in[6],  (const float*)d_in[11]};
    const float* Wh[3] = {(const float*)d_in[2], (const float*)d_in[7],  (const float*)d_in[12]};
    const float* bb[3] = {(const float*)d_in[3], (const float*)d_in[8],  (const float*)d_in[13]};
    const float* gg[3] = {(const float*)d_in[4], (const float*)d_in[9],  (const float*)d_in[14]};
    const float* be[3] = {(const float*)d_in[5], (const float*)d_in[10], (const float*)d_in[15]};

    float* ws    = (float*)d_ws;
    u16*  xg     = (u16*)ws;              // 8,388,608 u16 (8192 x 1024 fp16, n')
    float* cbuf  = ws   + 4194304;        //   262,144 f32
    float* hs    = cbuf + 262144;         // 2,097,152 f32
    float* part  = hs   + 2097152;        //    32,768 (64 x 512)
    float* stats = part + 262144;         //       512
    u16*  pad_x  = (u16*)(stats + 512);   // 32*18*18*256 fp16
    u16*  pad_h  = pad_x + 2654208;       // 2 x 331,776 (ping-pong)
    u16*  wTx    = pad_h + 663552;        // 1024*2304 (row-major, conv_big)
    u16*  wTf    = wTx   + 2359296;       // 64*72*512 (frag-packed, rec)
    const long PHN = 331776;

    hipMemsetAsync(pad_x, 0, 2654208 * sizeof(u16), stream);   // halos
    hipMemsetAsync(pad_h, 0, 2 * PHN * sizeof(u16), stream);   // halos (once)
    hipLaunchKernelGGL(convert_x_k, dim3(2048), dim3(256), 0, stream, x0, pad_x);

    for (int l = 0; l < 3; ++l) {
        hipLaunchKernelGGL(wprep_k, dim3(72, 4), dim3(256), 0, stream, Wx[l], wTx);
        hipLaunchKernelGGL(wprep_frag_k, dim3(72, 16), dim3(256), 0, stream, Wh[l], wTf);

        hipLaunchKernelGGL(conv_big_k, dim3(512), dim3(256), 0, stream,
            pad_x, wTx, bb[l], xg);

        // t = 0: gates-only (h0 = 0); writes ph buffer 1
        hipLaunchKernelGGL(gates0_k, dim3(1024), dim3(256), 0, stream,
            xg, cbuf, hs, pad_h + PHN);

        for (int t = 1; t < TSTEPS; ++t) {
            hipLaunchKernelGGL(rec_fused_k, dim3(256), dim3(256), 0, stream,
                pad_h + (t & 1) * PHN, wTf, xg, cbuf, hs,
                pad_h + ((t & 1) ^ 1) * PHN, t);
        }

        hipLaunchKernelGGL(bn_stats1_k, dim3(64), dim3(256), 0, stream, hs, part);
        hipLaunchKernelGGL(bn_stats2_k, dim3(1), dim3(256), 0, stream, part, gg[l], be[l], stats);
        hipLaunchKernelGGL(bn_apply_k, dim3(2048), dim3(256), 0, stream, hs, stats,
            (l < 2) ? pad_x : (u16*)nullptr, (l == 2) ? (float*)d_out : (float*)nullptr);
    }
}

// Round 8
// 541.784 us; speedup vs baseline: 2.1100x; 1.0229x over previous
//
#include <hip/hip_runtime.h>

// B=4, T=8, H=W=16, C=F=256, gates 4F=1024. K = 9*256 = 2304.
// Round 8: rec_v5 = 32x64 tiles, 512 blocks (2/CU), wave 16m x 32n, B in
// regs (frag-packed), A gl16->LDS depth-3, uniform counted vmcnt(5),
// 3-deep named B-register rotation. conv_big: two-barrier counted-vmcnt
// phase (stage latency hidden under previous compute).
#define HW      256
#define COUT    1024
#define TSTEPS  8
#define BN_EPS  1e-3f
#define KTOT    2304

typedef unsigned short u16;
typedef unsigned int   u32;
typedef __attribute__((ext_vector_type(8))) _Float16 v8h;  // 8 x fp16
typedef __attribute__((ext_vector_type(4))) float v4f;

__device__ __forceinline__ u16 f2h(float x) {
    _Float16 h = (_Float16)x; return *(u16*)&h;
}
__device__ __forceinline__ float h2f(u16 u) {
    _Float16 h = *(_Float16*)&u; return (float)h;
}
__device__ __forceinline__ float hsig(float x) {
    return fminf(fmaxf(0.2f * x + 0.5f, 0.f), 1.f);
}

typedef __attribute__((address_space(1))) const unsigned int gas_u32;
typedef __attribute__((address_space(3))) unsigned int las_u32;
__device__ __forceinline__ void gl16(const void* g, void* l) {
    __builtin_amdgcn_global_load_lds((gas_u32*)g, (las_u32*)l, 16, 0, 0);
}

// ---------------------------------------------------------------------------
// Big input conv: M=8192, N'=1024, BM=BN=128, BK=64, 4 waves (2x2),
// two-barrier counted-vmcnt phase, slot-swizzled LDS, 2 blk/CU.
// ---------------------------------------------------------------------------
__global__ __launch_bounds__(256, 2) void conv_big_k(
    const u16* __restrict__ apad,     // (32,18,18,256) fp16 zero-padded
    const u16* __restrict__ wT,       // (1024 n', 2304) fp16
    const float* __restrict__ bias,   // (1024) original n order
    u16* __restrict__ out)            // (8192, 1024) fp16, n' order
{
    constexpr int KQ = 36;
    __shared__ u16 lds[2 * 16384];

    const int bid = blockIdx.x;
    const int xcd = bid & 7, idx = bid >> 3;
    const int by = (xcd >> 1) * 2 + (idx & 1);
    const int bx = (xcd & 1) * 32 + (idx >> 1);
    const int m0 = bx * 128, n0 = by * 128;
    const int tid = threadIdx.x, lane = tid & 63, w = tid >> 6;
    const int wr = w >> 1, wc = w & 1;
    const int lr = lane >> 3;
    const int g  = (lane & 7) ^ lr;
    const int fr = lane & 15, kc = lane >> 4;

    const char* a_src[4];
    #pragma unroll
    for (int i = 0; i < 4; ++i) {
        int m = m0 + w * 32 + i * 8 + lr;
        int img = m >> 8, pix = m & 255, yy = pix >> 4, xx = pix & 15;
        a_src[i] = (const char*)apad + ((((long)img * 18 + yy) * 18 + xx) * 256 + g * 8) * 2;
    }
    const char* b_src[4];
    #pragma unroll
    for (int i = 0; i < 4; ++i) {
        int n = n0 + w * 32 + i * 8 + lr;
        b_src[i] = (const char*)wT + ((long)n * KTOT + g * 8) * 2;
    }

    int aro[4][2], bro[4][2];
    #pragma unroll
    for (int mi = 0; mi < 4; ++mi) {
        int rl = wr * 64 + mi * 16 + fr;
        #pragma unroll
        for (int ks = 0; ks < 2; ++ks)
            aro[mi][ks] = rl * 128 + ((((ks << 2) | kc) ^ (fr & 7)) << 4);
    }
    #pragma unroll
    for (int ni = 0; ni < 4; ++ni) {
        int nr = wc * 64 + ni * 16 + fr;
        #pragma unroll
        for (int ks = 0; ks < 2; ++ks)
            bro[ni][ks] = 16384 + nr * 128 + ((((ks << 2) | kc) ^ (fr & 7)) << 4);
    }

    v4f acc[4][4];
    #pragma unroll
    for (int mi = 0; mi < 4; ++mi)
        #pragma unroll
        for (int ni = 0; ni < 4; ++ni) acc[mi][ni] = (v4f)0.f;

#define STAGE_B(J) { int j_ = (J); int dxy = j_ >> 2, c64 = j_ & 3;           \
    int dy = (dxy * 11) >> 5; int dx = dxy - dy * 3;                          \
    int aoff = ((dy * 18 + dx) * 256 + c64 * 64) * 2; int boff = j_ * 128;    \
    char* base = (char*)lds + (j_ & 1) * 32768;                               \
    _Pragma("unroll") for (int i = 0; i < 4; ++i)                             \
        gl16(a_src[i] + aoff, base + (w * 32 + i * 8) * 128);                 \
    _Pragma("unroll") for (int i = 0; i < 4; ++i)                             \
        gl16(b_src[i] + boff, base + 16384 + (w * 32 + i * 8) * 128); }

#define COMPUTE_B(J) { const char* base = (const char*)lds + ((J) & 1) * 32768; \
    v8h af[4][2], bf[4][2];                                                   \
    _Pragma("unroll") for (int mi = 0; mi < 4; ++mi)                          \
        _Pragma("unroll") for (int ks = 0; ks < 2; ++ks)                      \
            af[mi][ks] = *(const v8h*)(base + aro[mi][ks]);                   \
    _Pragma("unroll") for (int ni = 0; ni < 4; ++ni)                          \
        _Pragma("unroll") for (int ks = 0; ks < 2; ++ks)                      \
            bf[ni][ks] = *(const v8h*)(base + bro[ni][ks]);                   \
    __builtin_amdgcn_s_setprio(1);                                            \
    _Pragma("unroll") for (int ks = 0; ks < 2; ++ks)                          \
    _Pragma("unroll") for (int mi = 0; mi < 4; ++mi)                          \
    _Pragma("unroll") for (int ni = 0; ni < 4; ++ni)                          \
        acc[mi][ni] = __builtin_amdgcn_mfma_f32_16x16x32_f16(af[mi][ks], bf[ni][ks], acc[mi][ni], 0, 0, 0); \
    __builtin_amdgcn_s_setprio(0); }

    STAGE_B(0);
    for (int kq = 0; kq < KQ; ++kq) {
        int jj = kq + 1 < KQ ? kq + 1 : KQ - 1;   // tail: dup-stage, unread buf
        __builtin_amdgcn_s_barrier();             // all reads of target buf done
        STAGE_B(jj);
        asm volatile("s_waitcnt vmcnt(8)" ::: "memory");  // stage kq landed (own)
        __builtin_amdgcn_s_barrier();             // stage kq landed (all waves)
        __builtin_amdgcn_sched_barrier(0);
        COMPUTE_B(kq);
    }
#undef STAGE_B
#undef COMPUTE_B

    #pragma unroll
    for (int mi = 0; mi < 4; ++mi) {
        #pragma unroll
        for (int ni = 0; ni < 4; ++ni) {
            int mrow = m0 + wr * 64 + mi * 16 + ((lane >> 4) << 2);
            int ncol = n0 + wc * 64 + ni * 16 + fr;
            float b0 = bias[(ncol & 3) * 256 + (ncol >> 2)];
            #pragma unroll
            for (int r = 0; r < 4; ++r)
                out[(long)(mrow + r) * COUT + ncol] = f2h(acc[mi][ni][r] + b0);
        }
    }
}

// ---------------------------------------------------------------------------
// Recurrent conv + fused LSTM cell, v5: 32x64 tile, 512 blocks (2/CU),
// 4 waves 2x2 (wave 16m x 32n). B frag-packed from L2 into regs (3-deep
// rotation); A gl16->LDS depth-3; uniform counted vmcnt(5).
// ---------------------------------------------------------------------------
__global__ __launch_bounds__(256, 2) void rec_fused_k(
    const u16* __restrict__ ph_in,    // (4,18,18,256) fp16  h_{t-1}
    const u16* __restrict__ wTf,      // frag-packed Wh: (64 nf, 72 k32, 512)
    const u16* __restrict__ xg,       // (8192, 1024) fp16, n' order (incl bias)
    float* __restrict__ cbuf,         // (4,256,256)
    float* __restrict__ hs,           // (4,8,256,256)
    u16* __restrict__ ph_out,         // (4,18,18,256) fp16  h_t
    int t)
{
    __shared__ u16 lds[3 * 2048];     // 3 bufs x 4KB (A only)

    const int bid = blockIdx.x;       // 512: by-pairs per XCD (bijective)
    const int by = (bid & 7) * 2 + ((bid >> 3) & 1);   // 0..15
    const int bx = bid >> 4;                           // 0..31
    const int m0 = bx * 32, n0 = by * 64;
    const int tid = threadIdx.x, lane = tid & 63, w = tid >> 6;
    const int wr = w >> 1, wc = w & 1;
    const int fr = lane & 15, kc = lane >> 4;

    // A staging: thread stages row rt = tid>>3, granule g (inverse swizzle)
    const char* a_src;
    {
        int rt = tid >> 3;
        int gg = (lane & 7) ^ (rt & 7);
        int m = m0 + rt;
        int img = m >> 8, pix = m & 255, yy = pix >> 4, xx = pix & 15;
        a_src = (const char*)ph_in + ((((long)img * 18 + yy) * 18 + xx) * 256 + gg * 8) * 2;
    }
    // B fragment bases: wave covers nf = by*4 + wc*2 + {0,1}
    const char* b_base0 = (const char*)wTf + ((long)(by * 4 + wc * 2 + 0) * 72) * 1024 + lane * 16;
    const char* b_base1 = (const char*)wTf + ((long)(by * 4 + wc * 2 + 1) * 72) * 1024 + lane * 16;

    // A frag read offsets (swizzled slot), rows wr*16 + fr
    int aro[2];
    #pragma unroll
    for (int ks = 0; ks < 2; ++ks)
        aro[ks] = (wr * 16 + fr) * 128 + ((((ks << 2) | kc) ^ (fr & 7)) << 4);

    v4f acc0 = (v4f)0.f, acc1 = (v4f)0.f;

#define STAGE_A(J) { int j_ = (J); int dxy = j_ >> 2, c64 = j_ & 3;           \
    int dy = (dxy * 11) >> 5; int dx = dxy - dy * 3;                          \
    int aoff = ((dy * 18 + dx) * 256 + c64 * 64) * 2;                         \
    gl16(a_src + aoff, (char*)lds + (j_ % 3) * 4096 + w * 1024); }

#define LDB(J, R00, R01, R10, R11) {                                          \
    R00 = *(const v8h*)(b_base0 + (2 * (J)) * 1024);                          \
    R01 = *(const v8h*)(b_base0 + (2 * (J) + 1) * 1024);                      \
    R10 = *(const v8h*)(b_base1 + (2 * (J)) * 1024);                          \
    R11 = *(const v8h*)(b_base1 + (2 * (J) + 1) * 1024); }

#define BODY(KQ, C00, C01, C10, C11, L00, L01, L10, L11) {                    \
    int kq_ = (KQ); int jj_ = kq_ + 2 < 36 ? kq_ + 2 : 35;                    \
    asm volatile("s_waitcnt vmcnt(5)" ::: "memory");                          \
    __builtin_amdgcn_s_barrier();                                             \
    __builtin_amdgcn_sched_barrier(0);                                        \
    LDB(jj_, L00, L01, L10, L11);                                             \
    STAGE_A(jj_);                                                             \
    const char* base_ = (const char*)lds + (kq_ % 3) * 4096;                  \
    v8h af0_ = *(const v8h*)(base_ + aro[0]);                                 \
    v8h af1_ = *(const v8h*)(base_ + aro[1]);                                 \
    __builtin_amdgcn_s_setprio(1);                                            \
    acc0 = __builtin_amdgcn_mfma_f32_16x16x32_f16(af0_, C00, acc0, 0, 0, 0);  \
    acc1 = __builtin_amdgcn_mfma_f32_16x16x32_f16(af0_, C10, acc1, 0, 0, 0);  \
    acc0 = __builtin_amdgcn_mfma_f32_16x16x32_f16(af1_, C01, acc0, 0, 0, 0);  \
    acc1 = __builtin_amdgcn_mfma_f32_16x16x32_f16(af1_, C11, acc1, 0, 0, 0);  \
    __builtin_amdgcn_s_setprio(0); }

    v8h A00, A01, A10, A11, B00, B01, B10, B11, C00, C01, C10, C11;
    LDB(0, A00, A01, A10, A11); STAGE_A(0);
    LDB(1, B00, B01, B10, B11); STAGE_A(1);
    for (int j = 0; j < 12; ++j) {
        int k0 = 3 * j;
        BODY(k0,     A00, A01, A10, A11, C00, C01, C10, C11);
        BODY(k0 + 1, B00, B01, B10, B11, A00, A01, A10, A11);
        BODY(k0 + 2, C00, C01, C10, C11, B00, B01, B10, B11);
    }
#undef STAGE_A
#undef LDB
#undef BODY

    // epilogue: quad-transpose (gate-lane <-> row-reg), + xg(fp16), cell update.
    v4f accA[2] = {acc0, acc1};
    const bool gl0 = lane & 1, gl1 = lane & 2;
    #pragma unroll
    for (int ni = 0; ni < 2; ++ni) {
        float V0 = accA[ni][0], V1 = accA[ni][1];
        float V2 = accA[ni][2], V3 = accA[ni][3];
        float x0 = __shfl_xor(V0, 1), x1 = __shfl_xor(V1, 1);
        float x2 = __shfl_xor(V2, 1), x3 = __shfl_xor(V3, 1);
        float a0 = gl0 ? x1 : V0;
        float a1 = gl0 ? V1 : x0;
        float a2 = gl0 ? x3 : V2;
        float a3 = gl0 ? V3 : x2;
        float s0 = __shfl_xor(a0, 2), s1 = __shfl_xor(a1, 2);
        float s2 = __shfl_xor(a2, 2), s3 = __shfl_xor(a3, 2);
        float Ti = gl1 ? s2 : a0;
        float Tf = gl1 ? s3 : a1;
        float Tc = gl1 ? a2 : s0;
        float To = gl1 ? a3 : s1;

        int row = m0 + wr * 16 + ((lane >> 4) << 2) + (lane & 3);
        int f4  = n0 + wc * 32 + ni * 16 + (lane & 12);
        int img = row >> 8, pix = row & 255, fch = f4 >> 2;
        long xrow = ((long)(img * TSTEPS + t) * HW + pix);
        uint2 xb = *(const uint2*)&xg[xrow * COUT + f4];
        float pi = Ti + h2f((u16)(xb.x & 0xffff));
        float pf = Tf + h2f((u16)(xb.x >> 16));
        float pc = Tc + h2f((u16)(xb.y & 0xffff));
        float po = To + h2f((u16)(xb.y >> 16));
        long cidx = (long)row * 256 + fch;
        float c = hsig(pf) * cbuf[cidx] + hsig(pi) * tanhf(pc);
        float h = hsig(po) * tanhf(c);
        cbuf[cidx] = c;
        hs[xrow * 256 + fch] = h;
        int yy = pix >> 4, xx = pix & 15;
        ph_out[(((long)img * 18 + yy + 1) * 18 + xx + 1) * 256 + fch] = f2h(h);
    }
}

// ---------------------------------------------------------------------------
// t=0 cell: h0=0 -> gates = xg only (no conv). Writes cbuf/hs/ph_out.
// ---------------------------------------------------------------------------
__global__ __launch_bounds__(256) void gates0_k(
    const u16* __restrict__ xg, float* __restrict__ cbuf,
    float* __restrict__ hs, u16* __restrict__ ph_out)
{
    int idx = blockIdx.x * 256 + threadIdx.x;     // 0..262143
    int fch = idx & 255, row = idx >> 8;
    int img = row >> 8, pix = row & 255;
    long xrow = (long)(img * TSTEPS) * HW + pix;
    uint2 xb = *(const uint2*)&xg[xrow * COUT + fch * 4];
    float pi = h2f((u16)(xb.x & 0xffff));
    float pc = h2f((u16)(xb.y & 0xffff));
    float po = h2f((u16)(xb.y >> 16));
    float c = hsig(pi) * tanhf(pc);
    float h = hsig(po) * tanhf(c);
    cbuf[(long)row * 256 + fch] = c;
    hs[xrow * 256 + fch] = h;
    int yy = pix >> 4, xx = pix & 15;
    ph_out[(((long)img * 18 + yy + 1) * 18 + xx + 1) * 256 + fch] = f2h(h);
}

// ---------------------------------------------------------------------------
// weight preps
// ---------------------------------------------------------------------------
__global__ __launch_bounds__(256) void wprep_k(const float* __restrict__ w,
                                               u16* __restrict__ wT)
{
    int k0 = blockIdx.x * 32;
    int np = blockIdx.y * 256 + threadIdx.x;      // n' row
    int n  = (np & 3) * 256 + (np >> 2);
    u32 pk[16];
    #pragma unroll
    for (int kk = 0; kk < 32; kk += 2) {
        float a = w[(long)(k0 + kk) * COUT + n];
        float b = w[(long)(k0 + kk + 1) * COUT + n];
        pk[kk >> 1] = (u32)f2h(a) | ((u32)f2h(b) << 16);
    }
    uint4* dst = (uint4*)&wT[(long)np * KTOT + k0];
    dst[0] = make_uint4(pk[0], pk[1], pk[2], pk[3]);
    dst[1] = make_uint4(pk[4], pk[5], pk[6], pk[7]);
    dst[2] = make_uint4(pk[8], pk[9], pk[10], pk[11]);
    dst[3] = make_uint4(pk[12], pk[13], pk[14], pk[15]);
}

// fragment-packed prep: wTf[((nf*72)+k32)*512 + l*8 + e] = Wh[k][n]
__global__ __launch_bounds__(256) void wprep_frag_k(const float* __restrict__ w,
                                                    u16* __restrict__ wTf)
{
    int kq = blockIdx.x;                       // 0..71
    int nf = blockIdx.y * 4 + (threadIdx.x >> 6);
    int l  = threadIdx.x & 63;
    int np = nf * 16 + (l & 15);
    int n  = (np & 3) * 256 + (np >> 2);
    int k0 = kq * 32 + (l >> 4) * 8;
    u32 pk[4];
    #pragma unroll
    for (int e = 0; e < 8; e += 2) {
        float a = w[(long)(k0 + e) * COUT + n];
        float b = w[(long)(k0 + e + 1) * COUT + n];
        pk[e >> 1] = (u32)f2h(a) | ((u32)f2h(b) << 16);
    }
    *(uint4*)&wTf[((long)(nf * 72) + kq) * 512 + l * 8] =
        make_uint4(pk[0], pk[1], pk[2], pk[3]);
}

// ---------------------------------------------------------------------------
// convert input x (32,16,16,256) fp32 -> pad_x interior fp16
// ---------------------------------------------------------------------------
__global__ __launch_bounds__(256) void convert_x_k(const float* __restrict__ x,
                                                   u16* __restrict__ padx)
{
    int q = blockIdx.x * 256 + threadIdx.x;
    int e0 = q * 4;
    int f = e0 & 255, pix = (e0 >> 8) & 255, img = e0 >> 16;
    float4 v = ((const float4*)x)[q];
    int yy = pix >> 4, xx = pix & 15;
    long o = (((long)img * 18 + yy + 1) * 18 + xx + 1) * 256 + f;
    u32 lo = (u32)f2h(v.x) | ((u32)f2h(v.y) << 16);
    u32 hi = (u32)f2h(v.z) | ((u32)f2h(v.w) << 16);
    *(uint2*)&padx[o] = make_uint2(lo, hi);
}

// ---------------------------------------------------------------------------
// BatchNorm: deterministic two-stage stats + apply
// ---------------------------------------------------------------------------
__global__ __launch_bounds__(256) void bn_stats1_k(
    const float* __restrict__ x, float* __restrict__ partial)
{
    const int tid = threadIdx.x;
    const int blk = blockIdx.x;                // 64 blocks
    float s = 0.f, s2 = 0.f;
    const long base = (long)blk * 128 * 256;
    #pragma unroll 8
    for (int gi = 0; gi < 128; ++gi) {
        float v = x[base + gi * 256 + tid];
        s += v; s2 += v * v;
    }
    partial[blk * 512 + tid]       = s;
    partial[blk * 512 + 256 + tid] = s2;
}

__global__ __launch_bounds__(256) void bn_stats2_k(
    const float* __restrict__ partial, const float* __restrict__ gamma,
    const float* __restrict__ beta, float* __restrict__ stats)
{
    const int f = threadIdx.x;
    float s = 0.f, s2 = 0.f;
    #pragma unroll 8
    for (int b = 0; b < 64; ++b) {
        s  += partial[b * 512 + f];
        s2 += partial[b * 512 + 256 + f];
    }
    const float inv_n = 1.f / 8192.f;
    float mu  = s * inv_n;
    float var = s2 * inv_n - mu * mu;
    float sc  = gamma[f] * rsqrtf(var + BN_EPS);
    stats[f]       = sc;
    stats[256 + f] = beta[f] - mu * sc;
}

__global__ __launch_bounds__(256) void bn_apply_k(
    const float* __restrict__ x, const float* __restrict__ stats,
    u16* __restrict__ padx, float* __restrict__ out)
{
    const int q = blockIdx.x * 256 + threadIdx.x;
    const int e0 = q * 4;
    const int f = e0 & 255, pix = (e0 >> 8) & 255, img = e0 >> 16;
    float4 v  = ((const float4*)x)[q];
    float4 sc = *(const float4*)(stats + f);
    float4 sh = *(const float4*)(stats + 256 + f);
    v.x = v.x * sc.x + sh.x;
    v.y = v.y * sc.y + sh.y;
    v.z = v.z * sc.z + sh.z;
    v.w = v.w * sc.w + sh.w;
    if (out) ((float4*)out)[q] = v;
    if (padx) {
        int yy = pix >> 4, xx = pix & 15;
        long o = (((long)img * 18 + yy + 1) * 18 + xx + 1) * 256 + f;
        u32 lo = (u32)f2h(v.x) | ((u32)f2h(v.y) << 16);
        u32 hi = (u32)f2h(v.z) | ((u32)f2h(v.w) << 16);
        *(uint2*)&padx[o] = make_uint2(lo, hi);
    }
}

// ---------------------------------------------------------------------------
extern "C" void kernel_launch(void* const* d_in, const int* in_sizes, int n_in,
                              void* d_out, int out_size, void* d_ws, size_t ws_size,
                              hipStream_t stream)
{
    const float* x0    = (const float*)d_in[0];
    const float* Wx[3] = {(const float*)d_in[1], (const float*)d_in[6],  (const float*)d_in[11]};
    const float* Wh[3] = {(const float*)d_in[2], (const float*)d_in[7],  (const float*)d_in[12]};
    const float* bb[3] = {(const float*)d_in[3], (const float*)d_in[8],  (const float*)d_in[13]};
    const float* gg[3] = {(const float*)d_in[4], (const float*)d_in[9],  (const float*)d_in[14]};
    const float* be[3] = {(const float*)d_in[5], (const float*)d_in[10], (const float*)d_in[15]};

    float* ws    = (float*)d_ws;
    u16*  xg     = (u16*)ws;              // 8,388,608 u16 (8192 x 1024 fp16, n')
    float* cbuf  = ws   + 4194304;        //   262,144 f32
    float* hs    = cbuf + 262144;         // 2,097,152 f32
    float* part  = hs   + 2097152;        //    32,768 (64 x 512)
    float* stats = part + 262144;         //       512
    u16*  pad_x  = (u16*)(stats + 512);   // 32*18*18*256 fp16
    u16*  pad_h  = pad_x + 2654208;       // 2 x 331,776 (ping-pong)
    u16*  wTx    = pad_h + 663552;        // 1024*2304 (row-major, conv_big)
    u16*  wTf    = wTx   + 2359296;       // 64*72*512 (frag-packed, rec)
    const long PHN = 331776;

    hipMemsetAsync(pad_x, 0, 2654208 * sizeof(u16), stream);   // halos
    hipMemsetAsync(pad_h, 0, 2 * PHN * sizeof(u16), stream);   // halos (once)
    hipLaunchKernelGGL(convert_x_k, dim3(2048), dim3(256), 0, stream, x0, pad_x);

    for (int l = 0; l < 3; ++l) {
        hipLaunchKernelGGL(wprep_k, dim3(72, 4), dim3(256), 0, stream, Wx[l], wTx);
        hipLaunchKernelGGL(wprep_frag_k, dim3(72, 16), dim3(256), 0, stream, Wh[l], wTf);

        hipLaunchKernelGGL(conv_big_k, dim3(512), dim3(256), 0, stream,
            pad_x, wTx, bb[l], xg);

        // t = 0: gates-only (h0 = 0); writes ph buffer 1
        hipLaunchKernelGGL(gates0_k, dim3(1024), dim3(256), 0, stream,
            xg, cbuf, hs, pad_h + PHN);

        for (int t = 1; t < TSTEPS; ++t) {
            hipLaunchKernelGGL(rec_fused_k, dim3(512), dim3(256), 0, stream,
                pad_h + (t & 1) * PHN, wTf, xg, cbuf, hs,
                pad_h + ((t & 1) ^ 1) * PHN, t);
        }

        hipLaunchKernelGGL(bn_stats1_k, dim3(64), dim3(256), 0, stream, hs, part);
        hipLaunchKernelGGL(bn_stats2_k, dim3(1), dim3(256), 0, stream, part, gg[l], be[l], stats);
        hipLaunchKernelGGL(bn_apply_k, dim3(2048), dim3(256), 0, stream, hs, stats,
            (l < 2) ? pad_x : (u16*)nullptr, (l == 2) ? (float*)d_out : (float*)nullptr);
    }
}

// Round 9
// 504.192 us; speedup vs baseline: 2.2673x; 1.0746x over previous
//
#include <hip/hip_runtime.h>

// B=4, T=8, H=W=16, C=F=256, gates 4F=1024. K = 9*256 = 2304.
// Round 9: rec_v6 = 64x64 tile, 256 blocks (1/CU), 8 waves (512 thr, 2m x 4n),
// wave 32m x 16n. B frag-packed in regs (1 nf per wave-col, 3-deep rotation),
// A gl16->LDS depth-3, uniform counted vmcnt(3). conv_big reverted to r6
// single-barrier loop.
#define HW      256
#define COUT    1024
#define TSTEPS  8
#define BN_EPS  1e-3f
#define KTOT    2304

typedef unsigned short u16;
typedef unsigned int   u32;
typedef __attribute__((ext_vector_type(8))) _Float16 v8h;  // 8 x fp16
typedef __attribute__((ext_vector_type(4))) float v4f;

__device__ __forceinline__ u16 f2h(float x) {
    _Float16 h = (_Float16)x; return *(u16*)&h;
}
__device__ __forceinline__ float h2f(u16 u) {
    _Float16 h = *(_Float16*)&u; return (float)h;
}
__device__ __forceinline__ float hsig(float x) {
    return fminf(fmaxf(0.2f * x + 0.5f, 0.f), 1.f);
}

typedef __attribute__((address_space(1))) const unsigned int gas_u32;
typedef __attribute__((address_space(3))) unsigned int las_u32;
__device__ __forceinline__ void gl16(const void* g, void* l) {
    __builtin_amdgcn_global_load_lds((gas_u32*)g, (las_u32*)l, 16, 0, 0);
}

// ---------------------------------------------------------------------------
// Big input conv: M=8192, N'=1024, BM=BN=128, BK=64, 4 waves (2x2),
// r6 single-barrier depth-2 pipeline, slot-swizzled LDS, 2 blk/CU.
// ---------------------------------------------------------------------------
__global__ __launch_bounds__(256, 2) void conv_big_k(
    const u16* __restrict__ apad,     // (32,18,18,256) fp16 zero-padded
    const u16* __restrict__ wT,       // (1024 n', 2304) fp16
    const float* __restrict__ bias,   // (1024) original n order
    u16* __restrict__ out)            // (8192, 1024) fp16, n' order
{
    constexpr int KQ = 36;
    __shared__ u16 lds[2 * 16384];

    const int bid = blockIdx.x;
    const int xcd = bid & 7, idx = bid >> 3;
    const int by = (xcd >> 1) * 2 + (idx & 1);
    const int bx = (xcd & 1) * 32 + (idx >> 1);
    const int m0 = bx * 128, n0 = by * 128;
    const int tid = threadIdx.x, lane = tid & 63, w = tid >> 6;
    const int wr = w >> 1, wc = w & 1;
    const int lr = lane >> 3;
    const int g  = (lane & 7) ^ lr;
    const int fr = lane & 15, kc = lane >> 4;

    const char* a_src[4];
    #pragma unroll
    for (int i = 0; i < 4; ++i) {
        int m = m0 + w * 32 + i * 8 + lr;
        int img = m >> 8, pix = m & 255, yy = pix >> 4, xx = pix & 15;
        a_src[i] = (const char*)apad + ((((long)img * 18 + yy) * 18 + xx) * 256 + g * 8) * 2;
    }
    const char* b_src[4];
    #pragma unroll
    for (int i = 0; i < 4; ++i) {
        int n = n0 + w * 32 + i * 8 + lr;
        b_src[i] = (const char*)wT + ((long)n * KTOT + g * 8) * 2;
    }

    int aro[4][2], bro[4][2];
    #pragma unroll
    for (int mi = 0; mi < 4; ++mi) {
        int rl = wr * 64 + mi * 16 + fr;
        #pragma unroll
        for (int ks = 0; ks < 2; ++ks)
            aro[mi][ks] = rl * 128 + ((((ks << 2) | kc) ^ (fr & 7)) << 4);
    }
    #pragma unroll
    for (int ni = 0; ni < 4; ++ni) {
        int nr = wc * 64 + ni * 16 + fr;
        #pragma unroll
        for (int ks = 0; ks < 2; ++ks)
            bro[ni][ks] = 16384 + nr * 128 + ((((ks << 2) | kc) ^ (fr & 7)) << 4);
    }

    v4f acc[4][4];
    #pragma unroll
    for (int mi = 0; mi < 4; ++mi)
        #pragma unroll
        for (int ni = 0; ni < 4; ++ni) acc[mi][ni] = (v4f)0.f;

#define STAGE_B(J) { int j_ = (J); int dxy = j_ >> 2, c64 = j_ & 3;           \
    int dy = (dxy * 11) >> 5; int dx = dxy - dy * 3;                          \
    int aoff = ((dy * 18 + dx) * 256 + c64 * 64) * 2; int boff = j_ * 128;    \
    char* base = (char*)lds + (j_ & 1) * 32768;                               \
    _Pragma("unroll") for (int i = 0; i < 4; ++i)                             \
        gl16(a_src[i] + aoff, base + (w * 32 + i * 8) * 128);                 \
    _Pragma("unroll") for (int i = 0; i < 4; ++i)                             \
        gl16(b_src[i] + boff, base + 16384 + (w * 32 + i * 8) * 128); }

#define COMPUTE_B(J) { const char* base = (const char*)lds + ((J) & 1) * 32768; \
    v8h af[4][2], bf[4][2];                                                   \
    _Pragma("unroll") for (int mi = 0; mi < 4; ++mi)                          \
        _Pragma("unroll") for (int ks = 0; ks < 2; ++ks)                      \
            af[mi][ks] = *(const v8h*)(base + aro[mi][ks]);                   \
    _Pragma("unroll") for (int ni = 0; ni < 4; ++ni)                          \
        _Pragma("unroll") for (int ks = 0; ks < 2; ++ks)                      \
            bf[ni][ks] = *(const v8h*)(base + bro[ni][ks]);                   \
    __builtin_amdgcn_s_setprio(1);                                            \
    _Pragma("unroll") for (int ks = 0; ks < 2; ++ks)                          \
    _Pragma("unroll") for (int mi = 0; mi < 4; ++mi)                          \
    _Pragma("unroll") for (int ni = 0; ni < 4; ++ni)                          \
        acc[mi][ni] = __builtin_amdgcn_mfma_f32_16x16x32_f16(af[mi][ks], bf[ni][ks], acc[mi][ni], 0, 0, 0); \
    __builtin_amdgcn_s_setprio(0); }

    STAGE_B(0);
    for (int kq = 0; kq < KQ - 1; ++kq) {
        asm volatile("s_waitcnt vmcnt(0)" ::: "memory");
        __builtin_amdgcn_s_barrier();
        __builtin_amdgcn_sched_barrier(0);
        STAGE_B(kq + 1);
        COMPUTE_B(kq);
    }
    asm volatile("s_waitcnt vmcnt(0)" ::: "memory");
    __builtin_amdgcn_s_barrier();
    __builtin_amdgcn_sched_barrier(0);
    COMPUTE_B(KQ - 1);
#undef STAGE_B
#undef COMPUTE_B

    #pragma unroll
    for (int mi = 0; mi < 4; ++mi) {
        #pragma unroll
        for (int ni = 0; ni < 4; ++ni) {
            int mrow = m0 + wr * 64 + mi * 16 + ((lane >> 4) << 2);
            int ncol = n0 + wc * 64 + ni * 16 + fr;
            float b0 = bias[(ncol & 3) * 256 + (ncol >> 2)];
            #pragma unroll
            for (int r = 0; r < 4; ++r)
                out[(long)(mrow + r) * COUT + ncol] = f2h(acc[mi][ni][r] + b0);
        }
    }
}

// ---------------------------------------------------------------------------
// Recurrent conv + fused LSTM cell, v6: 64x64 tile, 256 blocks (1/CU),
// 8 waves (512 thr, 2m x 4n), wave 32m x 16n. B frag-packed in regs
// (3-deep rotation, 1 nf per wave-col); A gl16->LDS depth-3; vmcnt(3).
// ---------------------------------------------------------------------------
__global__ __launch_bounds__(512) void rec_fused_k(
    const u16* __restrict__ ph_in,    // (4,18,18,256) fp16  h_{t-1}
    const u16* __restrict__ wTf,      // frag-packed Wh: (64 nf, 72 k32, 512)
    const u16* __restrict__ xg,       // (8192, 1024) fp16, n' order (incl bias)
    float* __restrict__ cbuf,         // (4,256,256)
    float* __restrict__ hs,           // (4,8,256,256)
    u16* __restrict__ ph_out,         // (4,18,18,256) fp16  h_t
    int t)
{
    __shared__ u16 lds[3 * 4096];     // 3 bufs x 8KB (A only)

    const int bid = blockIdx.x;       // 256: by-pairs per XCD (bijective)
    const int by = (bid & 7) * 2 + ((bid >> 3) & 1);   // 0..15
    const int bx = bid >> 4;                           // 0..15
    const int m0 = bx * 64, n0 = by * 64;
    const int tid = threadIdx.x, lane = tid & 63, w = tid >> 6;
    const int wr = w >> 2, wc = w & 3;
    const int fr = lane & 15, kc = lane >> 4;

    // A staging: thread stages row rt = tid>>3 (0..63), slot lane&7
    const char* a_src;
    {
        int rt = tid >> 3;
        int gg = (tid & 7) ^ (rt & 7);     // inverse swizzle on SOURCE granule
        int m = m0 + rt;
        int img = m >> 8, pix = m & 255, yy = pix >> 4, xx = pix & 15;
        a_src = (const char*)ph_in + ((((long)img * 18 + yy) * 18 + xx) * 256 + gg * 8) * 2;
    }
    // B fragment base: wave-col owns nf = by*4 + wc
    const char* b_base = (const char*)wTf + ((long)(by * 4 + wc) * 72) * 1024 + lane * 16;

    // A frag read offsets (swizzled slot), rows wr*32 + mi*16 + fr
    int aro[2][2];
    #pragma unroll
    for (int mi = 0; mi < 2; ++mi)
        #pragma unroll
        for (int ks = 0; ks < 2; ++ks)
            aro[mi][ks] = (wr * 32 + mi * 16 + fr) * 128 + ((((ks << 2) | kc) ^ (fr & 7)) << 4);

    v4f acc0 = (v4f)0.f, acc1 = (v4f)0.f;

#define STAGE_A(J) { int j_ = (J); int dxy = j_ >> 2, c64 = j_ & 3;           \
    int dy = (dxy * 11) >> 5; int dx = dxy - dy * 3;                          \
    int aoff = ((dy * 18 + dx) * 256 + c64 * 64) * 2;                         \
    gl16(a_src + aoff, (char*)lds + (j_ % 3) * 8192 + w * 1024); }

#define LDB(J, R0, R1) { R0 = *(const v8h*)(b_base + (2 * (J)) * 1024);       \
                         R1 = *(const v8h*)(b_base + (2 * (J) + 1) * 1024); }

#define BODY(KQ, C0, C1, L0, L1) {                                            \
    int kq_ = (KQ); int jj_ = kq_ + 2 < 36 ? kq_ + 2 : 35;                    \
    asm volatile("s_waitcnt vmcnt(3)" ::: "memory");                          \
    __builtin_amdgcn_s_barrier();                                             \
    __builtin_amdgcn_sched_barrier(0);                                        \
    LDB(jj_, L0, L1);                                                         \
    STAGE_A(jj_);                                                             \
    const char* base_ = (const char*)lds + (kq_ % 3) * 8192;                  \
    v8h af00_ = *(const v8h*)(base_ + aro[0][0]);                             \
    v8h af10_ = *(const v8h*)(base_ + aro[1][0]);                             \
    v8h af01_ = *(const v8h*)(base_ + aro[0][1]);                             \
    v8h af11_ = *(const v8h*)(base_ + aro[1][1]);                             \
    __builtin_amdgcn_s_setprio(1);                                            \
    acc0 = __builtin_amdgcn_mfma_f32_16x16x32_f16(af00_, C0, acc0, 0, 0, 0);  \
    acc1 = __builtin_amdgcn_mfma_f32_16x16x32_f16(af10_, C0, acc1, 0, 0, 0);  \
    acc0 = __builtin_amdgcn_mfma_f32_16x16x32_f16(af01_, C1, acc0, 0, 0, 0);  \
    acc1 = __builtin_amdgcn_mfma_f32_16x16x32_f16(af11_, C1, acc1, 0, 0, 0);  \
    __builtin_amdgcn_s_setprio(0); }

    v8h A0, A1, B0, B1, C0, C1;
    LDB(0, A0, A1); STAGE_A(0);
    LDB(1, B0, B1); STAGE_A(1);
    for (int j = 0; j < 12; ++j) {
        int k0 = 3 * j;
        BODY(k0,     A0, A1, C0, C1);
        BODY(k0 + 1, B0, B1, A0, A1);
        BODY(k0 + 2, C0, C1, B0, B1);
    }
#undef STAGE_A
#undef LDB
#undef BODY

    // epilogue: quad-transpose (gate-lane <-> row-reg), + xg(fp16), cell update.
    v4f accA[2] = {acc0, acc1};
    const bool gl0 = lane & 1, gl1 = lane & 2;
    #pragma unroll
    for (int mi = 0; mi < 2; ++mi) {
        float V0 = accA[mi][0], V1 = accA[mi][1];
        float V2 = accA[mi][2], V3 = accA[mi][3];
        float x0 = __shfl_xor(V0, 1), x1 = __shfl_xor(V1, 1);
        float x2 = __shfl_xor(V2, 1), x3 = __shfl_xor(V3, 1);
        float a0 = gl0 ? x1 : V0;
        float a1 = gl0 ? V1 : x0;
        float a2 = gl0 ? x3 : V2;
        float a3 = gl0 ? V3 : x2;
        float s0 = __shfl_xor(a0, 2), s1 = __shfl_xor(a1, 2);
        float s2 = __shfl_xor(a2, 2), s3 = __shfl_xor(a3, 2);
        float Ti = gl1 ? s2 : a0;
        float Tf = gl1 ? s3 : a1;
        float Tc = gl1 ? a2 : s0;
        float To = gl1 ? a3 : s1;

        int row = m0 + wr * 32 + mi * 16 + ((lane >> 4) << 2) + (lane & 3);
        int f4  = n0 + wc * 16 + (lane & 12);
        int img = row >> 8, pix = row & 255, fch = f4 >> 2;
        long xrow = ((long)(img * TSTEPS + t) * HW + pix);
        uint2 xb = *(const uint2*)&xg[xrow * COUT + f4];
        float pi = Ti + h2f((u16)(xb.x & 0xffff));
        float pf = Tf + h2f((u16)(xb.x >> 16));
        float pc = Tc + h2f((u16)(xb.y & 0xffff));
        float po = To + h2f((u16)(xb.y >> 16));
        long cidx = (long)row * 256 + fch;
        float c = hsig(pf) * cbuf[cidx] + hsig(pi) * tanhf(pc);
        float h = hsig(po) * tanhf(c);
        cbuf[cidx] = c;
        hs[xrow * 256 + fch] = h;
        int yy = pix >> 4, xx = pix & 15;
        ph_out[(((long)img * 18 + yy + 1) * 18 + xx + 1) * 256 + fch] = f2h(h);
    }
}

// ---------------------------------------------------------------------------
// t=0 cell: h0=0 -> gates = xg only (no conv). Writes cbuf/hs/ph_out.
// ---------------------------------------------------------------------------
__global__ __launch_bounds__(256) void gates0_k(
    const u16* __restrict__ xg, float* __restrict__ cbuf,
    float* __restrict__ hs, u16* __restrict__ ph_out)
{
    int idx = blockIdx.x * 256 + threadIdx.x;     // 0..262143
    int fch = idx & 255, row = idx >> 8;
    int img = row >> 8, pix = row & 255;
    long xrow = (long)(img * TSTEPS) * HW + pix;
    uint2 xb = *(const uint2*)&xg[xrow * COUT + fch * 4];
    float pi = h2f((u16)(xb.x & 0xffff));
    float pc = h2f((u16)(xb.y & 0xffff));
    float po = h2f((u16)(xb.y >> 16));
    float c = hsig(pi) * tanhf(pc);
    float h = hsig(po) * tanhf(c);
    cbuf[(long)row * 256 + fch] = c;
    hs[xrow * 256 + fch] = h;
    int yy = pix >> 4, xx = pix & 15;
    ph_out[(((long)img * 18 + yy + 1) * 18 + xx + 1) * 256 + fch] = f2h(h);
}

// ---------------------------------------------------------------------------
// weight preps
// ---------------------------------------------------------------------------
__global__ __launch_bounds__(256) void wprep_k(const float* __restrict__ w,
                                               u16* __restrict__ wT)
{
    int k0 = blockIdx.x * 32;
    int np = blockIdx.y * 256 + threadIdx.x;      // n' row
    int n  = (np & 3) * 256 + (np >> 2);
    u32 pk[16];
    #pragma unroll
    for (int kk = 0; kk < 32; kk += 2) {
        float a = w[(long)(k0 + kk) * COUT + n];
        float b = w[(long)(k0 + kk + 1) * COUT + n];
        pk[kk >> 1] = (u32)f2h(a) | ((u32)f2h(b) << 16);
    }
    uint4* dst = (uint4*)&wT[(long)np * KTOT + k0];
    dst[0] = make_uint4(pk[0], pk[1], pk[2], pk[3]);
    dst[1] = make_uint4(pk[4], pk[5], pk[6], pk[7]);
    dst[2] = make_uint4(pk[8], pk[9], pk[10], pk[11]);
    dst[3] = make_uint4(pk[12], pk[13], pk[14], pk[15]);
}

// fragment-packed prep: wTf[((nf*72)+k32)*512 + l*8 + e] = Wh[k][n]
__global__ __launch_bounds__(256) void wprep_frag_k(const float* __restrict__ w,
                                                    u16* __restrict__ wTf)
{
    int kq = blockIdx.x;                       // 0..71
    int nf = blockIdx.y * 4 + (threadIdx.x >> 6);
    int l  = threadIdx.x & 63;
    int np = nf * 16 + (l & 15);
    int n  = (np & 3) * 256 + (np >> 2);
    int k0 = kq * 32 + (l >> 4) * 8;
    u32 pk[4];
    #pragma unroll
    for (int e = 0; e < 8; e += 2) {
        float a = w[(long)(k0 + e) * COUT + n];
        float b = w[(long)(k0 + e + 1) * COUT + n];
        pk[e >> 1] = (u32)f2h(a) | ((u32)f2h(b) << 16);
    }
    *(uint4*)&wTf[((long)(nf * 72) + kq) * 512 + l * 8] =
        make_uint4(pk[0], pk[1], pk[2], pk[3]);
}

// ---------------------------------------------------------------------------
// convert input x (32,16,16,256) fp32 -> pad_x interior fp16
// ---------------------------------------------------------------------------
__global__ __launch_bounds__(256) void convert_x_k(const float* __restrict__ x,
                                                   u16* __restrict__ padx)
{
    int q = blockIdx.x * 256 + threadIdx.x;
    int e0 = q * 4;
    int f = e0 & 255, pix = (e0 >> 8) & 255, img = e0 >> 16;
    float4 v = ((const float4*)x)[q];
    int yy = pix >> 4, xx = pix & 15;
    long o = (((long)img * 18 + yy + 1) * 18 + xx + 1) * 256 + f;
    u32 lo = (u32)f2h(v.x) | ((u32)f2h(v.y) << 16);
    u32 hi = (u32)f2h(v.z) | ((u32)f2h(v.w) << 16);
    *(uint2*)&padx[o] = make_uint2(lo, hi);
}

// ---------------------------------------------------------------------------
// BatchNorm: deterministic two-stage stats + apply
// ---------------------------------------------------------------------------
__global__ __launch_bounds__(256) void bn_stats1_k(
    const float* __restrict__ x, float* __restrict__ partial)
{
    const int tid = threadIdx.x;
    const int blk = blockIdx.x;                // 64 blocks
    float s = 0.f, s2 = 0.f;
    const long base = (long)blk * 128 * 256;
    #pragma unroll 8
    for (int gi = 0; gi < 128; ++gi) {
        float v = x[base + gi * 256 + tid];
        s += v; s2 += v * v;
    }
    partial[blk * 512 + tid]       = s;
    partial[blk * 512 + 256 + tid] = s2;
}

__global__ __launch_bounds__(256) void bn_stats2_k(
    const float* __restrict__ partial, const float* __restrict__ gamma,
    const float* __restrict__ beta, float* __restrict__ stats)
{
    const int f = threadIdx.x;
    float s = 0.f, s2 = 0.f;
    #pragma unroll 8
    for (int b = 0; b < 64; ++b) {
        s  += partial[b * 512 + f];
        s2 += partial[b * 512 + 256 + f];
    }
    const float inv_n = 1.f / 8192.f;
    float mu  = s * inv_n;
    float var = s2 * inv_n - mu * mu;
    float sc  = gamma[f] * rsqrtf(var + BN_EPS);
    stats[f]       = sc;
    stats[256 + f] = beta[f] - mu * sc;
}

__global__ __launch_bounds__(256) void bn_apply_k(
    const float* __restrict__ x, const float* __restrict__ stats,
    u16* __restrict__ padx, float* __restrict__ out)
{
    const int q = blockIdx.x * 256 + threadIdx.x;
    const int e0 = q * 4;
    const int f = e0 & 255, pix = (e0 >> 8) & 255, img = e0 >> 16;
    float4 v  = ((const float4*)x)[q];
    float4 sc = *(const float4*)(stats + f);
    float4 sh = *(const float4*)(stats + 256 + f);
    v.x = v.x * sc.x + sh.x;
    v.y = v.y * sc.y + sh.y;
    v.z = v.z * sc.z + sh.z;
    v.w = v.w * sc.w + sh.w;
    if (out) ((float4*)out)[q] = v;
    if (padx) {
        int yy = pix >> 4, xx = pix & 15;
        long o = (((long)img * 18 + yy + 1) * 18 + xx + 1) * 256 + f;
        u32 lo = (u32)f2h(v.x) | ((u32)f2h(v.y) << 16);
        u32 hi = (u32)f2h(v.z) | ((u32)f2h(v.w) << 16);
        *(uint2*)&padx[o] = make_uint2(lo, hi);
    }
}

// ---------------------------------------------------------------------------
extern "C" void kernel_launch(void* const* d_in, const int* in_sizes, int n_in,
                              void* d_out, int out_size, void* d_ws, size_t ws_size,
                              hipStream_t stream)
{
    const float* x0    = (const float*)d_in[0];
    const float* Wx[3] = {(const float*)d_in[1], (const float*)d_in[6],  (const float*)d_in[11]};
    const float* Wh[3] = {(const float*)d_in[2], (const float*)d_in[7],  (const float*)d_in[12]};
    const float* bb[3] = {(const float*)d_in[3], (const float*)d_in[8],  (const float*)d_in[13]};
    const float* gg[3] = {(const float*)d_in[4], (const float*)d_in[9],  (const float*)d_in[14]};
    const float* be[3] = {(const float*)d_in[5], (const float*)d_in[10], (const float*)d_in[15]};

    float* ws    = (float*)d_ws;
    u16*  xg     = (u16*)ws;              // 8,388,608 u16 (8192 x 1024 fp16, n')
    float* cbuf  = ws   + 4194304;        //   262,144 f32
    float* hs    = cbuf + 262144;         // 2,097,152 f32
    float* part  = hs   + 2097152;        //    32,768 (64 x 512)
    float* stats = part + 262144;         //       512
    u16*  pad_x  = (u16*)(stats + 512);   // 32*18*18*256 fp16
    u16*  pad_h  = pad_x + 2654208;       // 2 x 331,776 (ping-pong)
    u16*  wTx    = pad_h + 663552;        // 1024*2304 (row-major, conv_big)
    u16*  wTf    = wTx   + 2359296;       // 64*72*512 (frag-packed, rec)
    const long PHN = 331776;

    hipMemsetAsync(pad_x, 0, 2654208 * sizeof(u16), stream);   // halos
    hipMemsetAsync(pad_h, 0, 2 * PHN * sizeof(u16), stream);   // halos (once)
    hipLaunchKernelGGL(convert_x_k, dim3(2048), dim3(256), 0, stream, x0, pad_x);

    for (int l = 0; l < 3; ++l) {
        hipLaunchKernelGGL(wprep_k, dim3(72, 4), dim3(256), 0, stream, Wx[l], wTx);
        hipLaunchKernelGGL(wprep_frag_k, dim3(72, 16), dim3(256), 0, stream, Wh[l], wTf);

        hipLaunchKernelGGL(conv_big_k, dim3(512), dim3(256), 0, stream,
            pad_x, wTx, bb[l], xg);

        // t = 0: gates-only (h0 = 0); writes ph buffer 1
        hipLaunchKernelGGL(gates0_k, dim3(1024), dim3(256), 0, stream,
            xg, cbuf, hs, pad_h + PHN);

        for (int t = 1; t < TSTEPS; ++t) {
            hipLaunchKernelGGL(rec_fused_k, dim3(256), dim3(512), 0, stream,
                pad_h + (t & 1) * PHN, wTf, xg, cbuf, hs,
                pad_h + ((t & 1) ^ 1) * PHN, t);
        }

        hipLaunchKernelGGL(bn_stats1_k, dim3(64), dim3(256), 0, stream, hs, part);
        hipLaunchKernelGGL(bn_stats2_k, dim3(1), dim3(256), 0, stream, part, gg[l], be[l], stats);
        hipLaunchKernelGGL(bn_apply_k, dim3(2048), dim3(256), 0, stream, hs, stats,
            (l < 2) ? pad_x : (u16*)nullptr, (l == 2) ? (float*)d_out : (float*)nullptr);
    }
}

// Round 11
// 470.307 us; speedup vs baseline: 2.4307x; 1.0720x over previous
//
#include <hip/hip_runtime.h>

// B=4, T=8, H=W=16, C=F=256, gates 4F=1024. K = 9*256 = 2304.
// Round 11: revert to round-9 structure (PASS, 504us); deepen rec pipeline
// to distance-3/depth-4: 4 LDS A-buffers, 4-deep B register rotation,
// uniform counted vmcnt(6), unroll-4 K-loop. conv_big unchanged (r6 loop).
#define HW      256
#define COUT    1024
#define TSTEPS  8
#define BN_EPS  1e-3f
#define KTOT    2304

typedef unsigned short u16;
typedef unsigned int   u32;
typedef __attribute__((ext_vector_type(8))) _Float16 v8h;  // 8 x fp16
typedef __attribute__((ext_vector_type(4))) float v4f;

__device__ __forceinline__ u16 f2h(float x) {
    _Float16 h = (_Float16)x; return *(u16*)&h;
}
__device__ __forceinline__ float h2f(u16 u) {
    _Float16 h = *(_Float16*)&u; return (float)h;
}
__device__ __forceinline__ float hsig(float x) {
    return fminf(fmaxf(0.2f * x + 0.5f, 0.f), 1.f);
}

typedef __attribute__((address_space(1))) const unsigned int gas_u32;
typedef __attribute__((address_space(3))) unsigned int las_u32;
__device__ __forceinline__ void gl16(const void* g, void* l) {
    __builtin_amdgcn_global_load_lds((gas_u32*)g, (las_u32*)l, 16, 0, 0);
}

// ---------------------------------------------------------------------------
// Big input conv: M=8192, N'=1024, BM=BN=128, BK=64, 4 waves (2x2),
// r6 single-barrier depth-2 pipeline, slot-swizzled LDS, 2 blk/CU.
// ---------------------------------------------------------------------------
__global__ __launch_bounds__(256, 2) void conv_big_k(
    const u16* __restrict__ apad,     // (32,18,18,256) fp16 zero-padded
    const u16* __restrict__ wT,       // (1024 n', 2304) fp16
    const float* __restrict__ bias,   // (1024) original n order
    u16* __restrict__ out)            // (8192, 1024) fp16, n' order
{
    constexpr int KQ = 36;
    __shared__ u16 lds[2 * 16384];

    const int bid = blockIdx.x;
    const int xcd = bid & 7, idx = bid >> 3;
    const int by = (xcd >> 1) * 2 + (idx & 1);
    const int bx = (xcd & 1) * 32 + (idx >> 1);
    const int m0 = bx * 128, n0 = by * 128;
    const int tid = threadIdx.x, lane = tid & 63, w = tid >> 6;
    const int wr = w >> 1, wc = w & 1;
    const int lr = lane >> 3;
    const int g  = (lane & 7) ^ lr;
    const int fr = lane & 15, kc = lane >> 4;

    const char* a_src[4];
    #pragma unroll
    for (int i = 0; i < 4; ++i) {
        int m = m0 + w * 32 + i * 8 + lr;
        int img = m >> 8, pix = m & 255, yy = pix >> 4, xx = pix & 15;
        a_src[i] = (const char*)apad + ((((long)img * 18 + yy) * 18 + xx) * 256 + g * 8) * 2;
    }
    const char* b_src[4];
    #pragma unroll
    for (int i = 0; i < 4; ++i) {
        int n = n0 + w * 32 + i * 8 + lr;
        b_src[i] = (const char*)wT + ((long)n * KTOT + g * 8) * 2;
    }

    int aro[4][2], bro[4][2];
    #pragma unroll
    for (int mi = 0; mi < 4; ++mi) {
        int rl = wr * 64 + mi * 16 + fr;
        #pragma unroll
        for (int ks = 0; ks < 2; ++ks)
            aro[mi][ks] = rl * 128 + ((((ks << 2) | kc) ^ (fr & 7)) << 4);
    }
    #pragma unroll
    for (int ni = 0; ni < 4; ++ni) {
        int nr = wc * 64 + ni * 16 + fr;
        #pragma unroll
        for (int ks = 0; ks < 2; ++ks)
            bro[ni][ks] = 16384 + nr * 128 + ((((ks << 2) | kc) ^ (fr & 7)) << 4);
    }

    v4f acc[4][4];
    #pragma unroll
    for (int mi = 0; mi < 4; ++mi)
        #pragma unroll
        for (int ni = 0; ni < 4; ++ni) acc[mi][ni] = (v4f)0.f;

#define STAGE_B(J) { int j_ = (J); int dxy = j_ >> 2, c64 = j_ & 3;           \
    int dy = (dxy * 11) >> 5; int dx = dxy - dy * 3;                          \
    int aoff = ((dy * 18 + dx) * 256 + c64 * 64) * 2; int boff = j_ * 128;    \
    char* base = (char*)lds + (j_ & 1) * 32768;                               \
    _Pragma("unroll") for (int i = 0; i < 4; ++i)                             \
        gl16(a_src[i] + aoff, base + (w * 32 + i * 8) * 128);                 \
    _Pragma("unroll") for (int i = 0; i < 4; ++i)                             \
        gl16(b_src[i] + boff, base + 16384 + (w * 32 + i * 8) * 128); }

#define COMPUTE_B(J) { const char* base = (const char*)lds + ((J) & 1) * 32768; \
    v8h af[4][2], bf[4][2];                                                   \
    _Pragma("unroll") for (int mi = 0; mi < 4; ++mi)                          \
        _Pragma("unroll") for (int ks = 0; ks < 2; ++ks)                      \
            af[mi][ks] = *(const v8h*)(base + aro[mi][ks]);                   \
    _Pragma("unroll") for (int ni = 0; ni < 4; ++ni)                          \
        _Pragma("unroll") for (int ks = 0; ks < 2; ++ks)                      \
            bf[ni][ks] = *(const v8h*)(base + bro[ni][ks]);                   \
    __builtin_amdgcn_s_setprio(1);                                            \
    _Pragma("unroll") for (int ks = 0; ks < 2; ++ks)                          \
    _Pragma("unroll") for (int mi = 0; mi < 4; ++mi)                          \
    _Pragma("unroll") for (int ni = 0; ni < 4; ++ni)                          \
        acc[mi][ni] = __builtin_amdgcn_mfma_f32_16x16x32_f16(af[mi][ks], bf[ni][ks], acc[mi][ni], 0, 0, 0); \
    __builtin_amdgcn_s_setprio(0); }

    STAGE_B(0);
    for (int kq = 0; kq < KQ - 1; ++kq) {
        asm volatile("s_waitcnt vmcnt(0)" ::: "memory");
        __builtin_amdgcn_s_barrier();
        __builtin_amdgcn_sched_barrier(0);
        STAGE_B(kq + 1);
        COMPUTE_B(kq);
    }
    asm volatile("s_waitcnt vmcnt(0)" ::: "memory");
    __builtin_amdgcn_s_barrier();
    __builtin_amdgcn_sched_barrier(0);
    COMPUTE_B(KQ - 1);
#undef STAGE_B
#undef COMPUTE_B

    #pragma unroll
    for (int mi = 0; mi < 4; ++mi) {
        #pragma unroll
        for (int ni = 0; ni < 4; ++ni) {
            int mrow = m0 + wr * 64 + mi * 16 + ((lane >> 4) << 2);
            int ncol = n0 + wc * 64 + ni * 16 + fr;
            float b0 = bias[(ncol & 3) * 256 + (ncol >> 2)];
            #pragma unroll
            for (int r = 0; r < 4; ++r)
                out[(long)(mrow + r) * COUT + ncol] = f2h(acc[mi][ni][r] + b0);
        }
    }
}

// ---------------------------------------------------------------------------
// Recurrent conv + fused LSTM cell, v7: 64x64 tile, 256 blocks (1/CU),
// 8 waves (512 thr, 2m x 4n), wave 32m x 16n. Distance-3/depth-4 pipeline:
// 4 LDS A-buffers, 4-deep B register rotation, uniform counted vmcnt(6).
// ---------------------------------------------------------------------------
__global__ __launch_bounds__(512) void rec_fused_k(
    const u16* __restrict__ ph_in,    // (4,18,18,256) fp16  h_{t-1}
    const u16* __restrict__ wTf,      // frag-packed Wh: (64 nf, 72 k32, 512)
    const u16* __restrict__ xg,       // (8192, 1024) fp16, n' order (incl bias)
    float* __restrict__ cbuf,         // (4,256,256)
    float* __restrict__ hs,           // (4,8,256,256)
    u16* __restrict__ ph_out,         // (4,18,18,256) fp16  h_t
    int t)
{
    __shared__ u16 lds[4 * 4096];     // 4 bufs x 8KB (A only)

    const int bid = blockIdx.x;       // 256: by-pairs per XCD (bijective)
    const int by = (bid & 7) * 2 + ((bid >> 3) & 1);   // 0..15
    const int bx = bid >> 4;                           // 0..15
    const int m0 = bx * 64, n0 = by * 64;
    const int tid = threadIdx.x, lane = tid & 63, w = tid >> 6;
    const int wr = w >> 2, wc = w & 3;
    const int fr = lane & 15, kc = lane >> 4;

    // A staging: thread stages row rt = tid>>3 (0..63), slot lane&7
    const char* a_src;
    {
        int rt = tid >> 3;
        int gg = (tid & 7) ^ (rt & 7);     // inverse swizzle on SOURCE granule
        int m = m0 + rt;
        int img = m >> 8, pix = m & 255, yy = pix >> 4, xx = pix & 15;
        a_src = (const char*)ph_in + ((((long)img * 18 + yy) * 18 + xx) * 256 + gg * 8) * 2;
    }
    // B fragment base: wave-col owns nf = by*4 + wc
    const char* b_base = (const char*)wTf + ((long)(by * 4 + wc) * 72) * 1024 + lane * 16;

    // A frag read offsets (swizzled slot), rows wr*32 + mi*16 + fr
    int aro[2][2];
    #pragma unroll
    for (int mi = 0; mi < 2; ++mi)
        #pragma unroll
        for (int ks = 0; ks < 2; ++ks)
            aro[mi][ks] = (wr * 32 + mi * 16 + fr) * 128 + ((((ks << 2) | kc) ^ (fr & 7)) << 4);

    v4f acc0 = (v4f)0.f, acc1 = (v4f)0.f;

#define STAGE_A(J) { int j_ = (J); int dxy = j_ >> 2, c64 = j_ & 3;           \
    int dy = (dxy * 11) >> 5; int dx = dxy - dy * 3;                          \
    int aoff = ((dy * 18 + dx) * 256 + c64 * 64) * 2;                         \
    gl16(a_src + aoff, (char*)lds + (j_ & 3) * 8192 + w * 1024); }

#define LDB(J, R0, R1) { R0 = *(const v8h*)(b_base + (2 * (J)) * 1024);       \
                         R1 = *(const v8h*)(b_base + (2 * (J) + 1) * 1024); }

#define BODY(KQ, C0, C1, L0, L1) {                                            \
    int kq_ = (KQ); int jj_ = kq_ + 3 < 36 ? kq_ + 3 : 35;                    \
    asm volatile("s_waitcnt vmcnt(6)" ::: "memory");                          \
    __builtin_amdgcn_s_barrier();                                             \
    __builtin_amdgcn_sched_barrier(0);                                        \
    LDB(jj_, L0, L1);                                                         \
    STAGE_A(jj_);                                                             \
    const char* base_ = (const char*)lds + (kq_ & 3) * 8192;                  \
    v8h af00_ = *(const v8h*)(base_ + aro[0][0]);                             \
    v8h af10_ = *(const v8h*)(base_ + aro[1][0]);                             \
    v8h af01_ = *(const v8h*)(base_ + aro[0][1]);                             \
    v8h af11_ = *(const v8h*)(base_ + aro[1][1]);                             \
    __builtin_amdgcn_s_setprio(1);                                            \
    acc0 = __builtin_amdgcn_mfma_f32_16x16x32_f16(af00_, C0, acc0, 0, 0, 0);  \
    acc1 = __builtin_amdgcn_mfma_f32_16x16x32_f16(af10_, C0, acc1, 0, 0, 0);  \
    acc0 = __builtin_amdgcn_mfma_f32_16x16x32_f16(af01_, C1, acc0, 0, 0, 0);  \
    acc1 = __builtin_amdgcn_mfma_f32_16x16x32_f16(af11_, C1, acc1, 0, 0, 0);  \
    __builtin_amdgcn_s_setprio(0); }

    v8h S00, S01, S10, S11, S20, S21, S30, S31;
    LDB(0, S00, S01); STAGE_A(0);
    LDB(1, S10, S11); STAGE_A(1);
    LDB(2, S20, S21); STAGE_A(2);
    for (int j = 0; j < 9; ++j) {
        int k0 = 4 * j;
        BODY(k0,     S00, S01, S30, S31);
        BODY(k0 + 1, S10, S11, S00, S01);
        BODY(k0 + 2, S20, S21, S10, S11);
        BODY(k0 + 3, S30, S31, S20, S21);
    }
#undef STAGE_A
#undef LDB
#undef BODY

    // epilogue: quad-transpose (gate-lane <-> row-reg), + xg(fp16), cell update.
    v4f accA[2] = {acc0, acc1};
    const bool gl0 = lane & 1, gl1 = lane & 2;
    #pragma unroll
    for (int mi = 0; mi < 2; ++mi) {
        float V0 = accA[mi][0], V1 = accA[mi][1];
        float V2 = accA[mi][2], V3 = accA[mi][3];
        float x0 = __shfl_xor(V0, 1), x1 = __shfl_xor(V1, 1);
        float x2 = __shfl_xor(V2, 1), x3 = __shfl_xor(V3, 1);
        float a0 = gl0 ? x1 : V0;
        float a1 = gl0 ? V1 : x0;
        float a2 = gl0 ? x3 : V2;
        float a3 = gl0 ? V3 : x2;
        float s0 = __shfl_xor(a0, 2), s1 = __shfl_xor(a1, 2);
        float s2 = __shfl_xor(a2, 2), s3 = __shfl_xor(a3, 2);
        float Ti = gl1 ? s2 : a0;
        float Tf = gl1 ? s3 : a1;
        float Tc = gl1 ? a2 : s0;
        float To = gl1 ? a3 : s1;

        int row = m0 + wr * 32 + mi * 16 + ((lane >> 4) << 2) + (lane & 3);
        int f4  = n0 + wc * 16 + (lane & 12);
        int img = row >> 8, pix = row & 255, fch = f4 >> 2;
        long xrow = ((long)(img * TSTEPS + t) * HW + pix);
        uint2 xb = *(const uint2*)&xg[xrow * COUT + f4];
        float pi = Ti + h2f((u16)(xb.x & 0xffff));
        float pf = Tf + h2f((u16)(xb.x >> 16));
        float pc = Tc + h2f((u16)(xb.y & 0xffff));
        float po = To + h2f((u16)(xb.y >> 16));
        long cidx = (long)row * 256 + fch;
        float c = hsig(pf) * cbuf[cidx] + hsig(pi) * tanhf(pc);
        float h = hsig(po) * tanhf(c);
        cbuf[cidx] = c;
        hs[xrow * 256 + fch] = h;
        int yy = pix >> 4, xx = pix & 15;
        ph_out[(((long)img * 18 + yy + 1) * 18 + xx + 1) * 256 + fch] = f2h(h);
    }
}

// ---------------------------------------------------------------------------
// t=0 cell: h0=0 -> gates = xg only (no conv). Writes cbuf/hs/ph_out.
// ---------------------------------------------------------------------------
__global__ __launch_bounds__(256) void gates0_k(
    const u16* __restrict__ xg, float* __restrict__ cbuf,
    float* __restrict__ hs, u16* __restrict__ ph_out)
{
    int idx = blockIdx.x * 256 + threadIdx.x;     // 0..262143
    int fch = idx & 255, row = idx >> 8;
    int img = row >> 8, pix = row & 255;
    long xrow = (long)(img * TSTEPS) * HW + pix;
    uint2 xb = *(const uint2*)&xg[xrow * COUT + fch * 4];
    float pi = h2f((u16)(xb.x & 0xffff));
    float pc = h2f((u16)(xb.y & 0xffff));
    float po = h2f((u16)(xb.y >> 16));
    float c = hsig(pi) * tanhf(pc);
    float h = hsig(po) * tanhf(c);
    cbuf[(long)row * 256 + fch] = c;
    hs[xrow * 256 + fch] = h;
    int yy = pix >> 4, xx = pix & 15;
    ph_out[(((long)img * 18 + yy + 1) * 18 + xx + 1) * 256 + fch] = f2h(h);
}

// ---------------------------------------------------------------------------
// weight preps
// ---------------------------------------------------------------------------
__global__ __launch_bounds__(256) void wprep_k(const float* __restrict__ w,
                                               u16* __restrict__ wT)
{
    int k0 = blockIdx.x * 32;
    int np = blockIdx.y * 256 + threadIdx.x;      // n' row
    int n  = (np & 3) * 256 + (np >> 2);
    u32 pk[16];
    #pragma unroll
    for (int kk = 0; kk < 32; kk += 2) {
        float a = w[(long)(k0 + kk) * COUT + n];
        float b = w[(long)(k0 + kk + 1) * COUT + n];
        pk[kk >> 1] = (u32)f2h(a) | ((u32)f2h(b) << 16);
    }
    uint4* dst = (uint4*)&wT[(long)np * KTOT + k0];
    dst[0] = make_uint4(pk[0], pk[1], pk[2], pk[3]);
    dst[1] = make_uint4(pk[4], pk[5], pk[6], pk[7]);
    dst[2] = make_uint4(pk[8], pk[9], pk[10], pk[11]);
    dst[3] = make_uint4(pk[12], pk[13], pk[14], pk[15]);
}

// fragment-packed prep: wTf[((nf*72)+k32)*512 + l*8 + e] = Wh[k][n]
__global__ __launch_bounds__(256) void wprep_frag_k(const float* __restrict__ w,
                                                    u16* __restrict__ wTf)
{
    int kq = blockIdx.x;                       // 0..71
    int nf = blockIdx.y * 4 + (threadIdx.x >> 6);
    int l  = threadIdx.x & 63;
    int np = nf * 16 + (l & 15);
    int n  = (np & 3) * 256 + (np >> 2);
    int k0 = kq * 32 + (l >> 4) * 8;
    u32 pk[4];
    #pragma unroll
    for (int e = 0; e < 8; e += 2) {
        float a = w[(long)(k0 + e) * COUT + n];
        float b = w[(long)(k0 + e + 1) * COUT + n];
        pk[e >> 1] = (u32)f2h(a) | ((u32)f2h(b) << 16);
    }
    *(uint4*)&wTf[((long)(nf * 72) + kq) * 512 + l * 8] =
        make_uint4(pk[0], pk[1], pk[2], pk[3]);
}

// ---------------------------------------------------------------------------
// convert input x (32,16,16,256) fp32 -> pad_x interior fp16
// ---------------------------------------------------------------------------
__global__ __launch_bounds__(256) void convert_x_k(const float* __restrict__ x,
                                                   u16* __restrict__ padx)
{
    int q = blockIdx.x * 256 + threadIdx.x;
    int e0 = q * 4;
    int f = e0 & 255, pix = (e0 >> 8) & 255, img = e0 >> 16;
    float4 v = ((const float4*)x)[q];
    int yy = pix >> 4, xx = pix & 15;
    long o = (((long)img * 18 + yy + 1) * 18 + xx + 1) * 256 + f;
    u32 lo = (u32)f2h(v.x) | ((u32)f2h(v.y) << 16);
    u32 hi = (u32)f2h(v.z) | ((u32)f2h(v.w) << 16);
    *(uint2*)&padx[o] = make_uint2(lo, hi);
}

// ---------------------------------------------------------------------------
// BatchNorm: deterministic two-stage stats + apply
// ---------------------------------------------------------------------------
__global__ __launch_bounds__(256) void bn_stats1_k(
    const float* __restrict__ x, float* __restrict__ partial)
{
    const int tid = threadIdx.x;
    const int blk = blockIdx.x;                // 64 blocks
    float s = 0.f, s2 = 0.f;
    const long base = (long)blk * 128 * 256;
    #pragma unroll 8
    for (int gi = 0; gi < 128; ++gi) {
        float v = x[base + gi * 256 + tid];
        s += v; s2 += v * v;
    }
    partial[blk * 512 + tid]       = s;
    partial[blk * 512 + 256 + tid] = s2;
}

__global__ __launch_bounds__(256) void bn_stats2_k(
    const float* __restrict__ partial, const float* __restrict__ gamma,
    const float* __restrict__ beta, float* __restrict__ stats)
{
    const int f = threadIdx.x;
    float s = 0.f, s2 = 0.f;
    #pragma unroll 8
    for (int b = 0; b < 64; ++b) {
        s  += partial[b * 512 + f];
        s2 += partial[b * 512 + 256 + f];
    }
    const float inv_n = 1.f / 8192.f;
    float mu  = s * inv_n;
    float var = s2 * inv_n - mu * mu;
    float sc  = gamma[f] * rsqrtf(var + BN_EPS);
    stats[f]       = sc;
    stats[256 + f] = beta[f] - mu * sc;
}

__global__ __launch_bounds__(256) void bn_apply_k(
    const float* __restrict__ x, const float* __restrict__ stats,
    u16* __restrict__ padx, float* __restrict__ out)
{
    const int q = blockIdx.x * 256 + threadIdx.x;
    const int e0 = q * 4;
    const int f = e0 & 255, pix = (e0 >> 8) & 255, img = e0 >> 16;
    float4 v  = ((const float4*)x)[q];
    float4 sc = *(const float4*)(stats + f);
    float4 sh = *(const float4*)(stats + 256 + f);
    v.x = v.x * sc.x + sh.x;
    v.y = v.y * sc.y + sh.y;
    v.z = v.z * sc.z + sh.z;
    v.w = v.w * sc.w + sh.w;
    if (out) ((float4*)out)[q] = v;
    if (padx) {
        int yy = pix >> 4, xx = pix & 15;
        long o = (((long)img * 18 + yy + 1) * 18 + xx + 1) * 256 + f;
        u32 lo = (u32)f2h(v.x) | ((u32)f2h(v.y) << 16);
        u32 hi = (u32)f2h(v.z) | ((u32)f2h(v.w) << 16);
        *(uint2*)&padx[o] = make_uint2(lo, hi);
    }
}

// ---------------------------------------------------------------------------
extern "C" void kernel_launch(void* const* d_in, const int* in_sizes, int n_in,
                              void* d_out, int out_size, void* d_ws, size_t ws_size,
                              hipStream_t stream)
{
    const float* x0    = (const float*)d_in[0];
    const float* Wx[3] = {(const float*)d_in[1], (const float*)d_in[6],  (const float*)d_in[11]};
    const float* Wh[3] = {(const float*)d_in[2], (const float*)d_in[7],  (const float*)d_in[12]};
    const float* bb[3] = {(const float*)d_in[3], (const float*)d_in[8],  (const float*)d_in[13]};
    const float* gg[3] = {(const float*)d_in[4], (const float*)d_in[9],  (const float*)d_in[14]};
    const float* be[3] = {(const float*)d_in[5], (const float*)d_in[10], (const float*)d_in[15]};

    float* ws    = (float*)d_ws;
    u16*  xg     = (u16*)ws;              // 8,388,608 u16 (8192 x 1024 fp16, n')
    float* cbuf  = ws   + 4194304;        //   262,144 f32
    float* hs    = cbuf + 262144;         // 2,097,152 f32
    float* part  = hs   + 2097152;        //    32,768 (64 x 512)
    float* stats = part + 262144;         //       512
    u16*  pad_x  = (u16*)(stats + 512);   // 32*18*18*256 fp16
    u16*  pad_h  = pad_x + 2654208;       // 2 x 331,776 (ping-pong)
    u16*  wTx    = pad_h + 663552;        // 1024*2304 (row-major, conv_big)
    u16*  wTf    = wTx   + 2359296;       // 64*72*512 (frag-packed, rec)
    const long PHN = 331776;

    hipMemsetAsync(pad_x, 0, 2654208 * sizeof(u16), stream);   // halos
    hipMemsetAsync(pad_h, 0, 2 * PHN * sizeof(u16), stream);   // halos (once)
    hipLaunchKernelGGL(convert_x_k, dim3(2048), dim3(256), 0, stream, x0, pad_x);

    for (int l = 0; l < 3; ++l) {
        hipLaunchKernelGGL(wprep_k, dim3(72, 4), dim3(256), 0, stream, Wx[l], wTx);
        hipLaunchKernelGGL(wprep_frag_k, dim3(72, 16), dim3(256), 0, stream, Wh[l], wTf);

        hipLaunchKernelGGL(conv_big_k, dim3(512), dim3(256), 0, stream,
            pad_x, wTx, bb[l], xg);

        // t = 0: gates-only (h0 = 0); writes ph buffer 1
        hipLaunchKernelGGL(gates0_k, dim3(1024), dim3(256), 0, stream,
            xg, cbuf, hs, pad_h + PHN);

        for (int t = 1; t < TSTEPS; ++t) {
            hipLaunchKernelGGL(rec_fused_k, dim3(256), dim3(512), 0, stream,
                pad_h + (t & 1) * PHN, wTf, xg, cbuf, hs,
                pad_h + ((t & 1) ^ 1) * PHN, t);
        }

        hipLaunchKernelGGL(bn_stats1_k, dim3(64), dim3(256), 0, stream, hs, part);
        hipLaunchKernelGGL(bn_stats2_k, dim3(1), dim3(256), 0, stream, part, gg[l], be[l], stats);
        hipLaunchKernelGGL(bn_apply_k, dim3(2048), dim3(256), 0, stream, hs, stats,
            (l < 2) ? pad_x : (u16*)nullptr, (l == 2) ? (float*)d_out : (float*)nullptr);
    }
}